// Round 5
// baseline (1352.610 us; speedup 1.0000x reference)
//
#include <hip/hip_runtime.h>
#include <stdint.h>

#define T_Q   2048
#define N_REF 16384
#define DIM   768
#define KP2   1536        // packed K cols: [hi | lo]
#define NT    72          // logical K' = 2304 = 72 tiles of 32
#define BM    256
#define BN    256
#define NL    256         // partial top-4 lists per query

using f16   = _Float16;
using f16x4 = __attribute__((ext_vector_type(4))) _Float16;
using f16x8 = __attribute__((ext_vector_type(8))) _Float16;
using f32x4 = __attribute__((ext_vector_type(4))) float;

// ---------- lexicographic top-4 helpers (static indices only) ----------
__device__ __forceinline__ bool lex_less(float sa, int ia, float sb, int ib) {
  return (sa < sb) || (sa == sb && ia < ib);
}
#define CE_PAIR(s0, i0, s1, i1)                                        \
  { if (lex_less(s1, i1, s0, i0)) { float _ts = s0; s0 = s1; s1 = _ts; \
                                    int _ti = i0; i0 = i1; i1 = _ti; } }
#define PICKMIN(as, ai, bs, bi, rs, ri)                   \
  { if (lex_less(bs, bi, as, ai)) { rs = bs; ri = bi; }   \
    else                          { rs = as; ri = ai; } }

__device__ __forceinline__ void insert4(float s[4], int id[4], float sc, int n) {
  if (lex_less(sc, n, s[3], id[3])) {
    s[3] = sc; id[3] = n;
    CE_PAIR(s[2], id[2], s[3], id[3]);
    CE_PAIR(s[1], id[1], s[2], id[2]);
    CE_PAIR(s[0], id[0], s[1], id[1]);
  }
}
__device__ __forceinline__ void merge_top4(float s[4], int id[4],
                                           const float os[4], const int oid[4]) {
  float l0, l1, l2, l3; int j0, j1, j2, j3;
  PICKMIN(s[0], id[0], os[3], oid[3], l0, j0);
  PICKMIN(s[1], id[1], os[2], oid[2], l1, j1);
  PICKMIN(s[2], id[2], os[1], oid[1], l2, j2);
  PICKMIN(s[3], id[3], os[0], oid[0], l3, j3);
  CE_PAIR(l0, j0, l2, j2);
  CE_PAIR(l1, j1, l3, j3);
  CE_PAIR(l0, j0, l1, j1);
  CE_PAIR(l2, j2, l3, j3);
  s[0] = l0; s[1] = l1; s[2] = l2; s[3] = l3;
  id[0] = j0; id[1] = j1; id[2] = j2; id[3] = j3;
}

__device__ __forceinline__ void gl_lds16(const void* g, void* l) {
  __builtin_amdgcn_global_load_lds((const __attribute__((address_space(1))) uint32_t*)g,
                                   (__attribute__((address_space(3))) uint32_t*)l, 16, 0, 0);
}

// ---------- r2[n] = ||ref_n||^2 (fp32 exact) ----------
__global__ __launch_bounds__(256)
void r2_kernel(const float* __restrict__ R, float* __restrict__ r2) {
  __shared__ float red[256];
  const int lane = threadIdx.x & 63;
  const int dg   = threadIdx.x >> 6;
  const int n    = blockIdx.x * 64 + lane;
  float acc = 0.f;
  const int d0 = dg * (DIM / 4), d1 = d0 + (DIM / 4);
  for (int d = d0; d < d1; ++d) {
    float v = R[(size_t)d * N_REF + n];
    acc += v * v;
  }
  red[threadIdx.x] = acc;
  __syncthreads();
  if (threadIdx.x < 64)
    r2[n] = red[lane] + red[lane + 64] + red[lane + 128] + red[lane + 192];
}

// ---------- transpose + f16 hi/lo split: in[D][W] -> out[W][1536] = [hi | lo] ----------
__global__ __launch_bounds__(256)
void tsplit_kernel(const float* __restrict__ in, f16* __restrict__ out, int W) {
  __shared__ f16 lh[64][66], ll[64][66];
  const int c0 = blockIdx.x * 64, d0 = blockIdx.y * 64;
  const int q = threadIdx.x & 15, p = threadIdx.x >> 4;
#pragma unroll
  for (int i = 0; i < 4; ++i) {
    const int dl = p + i * 16;
    const float4 v = *(const float4*)&in[(size_t)(d0 + dl) * W + c0 + q * 4];
    const f16 h0 = (f16)v.x, h1 = (f16)v.y, h2 = (f16)v.z, h3 = (f16)v.w;
    lh[q * 4 + 0][dl] = h0; ll[q * 4 + 0][dl] = (f16)(v.x - (float)h0);
    lh[q * 4 + 1][dl] = h1; ll[q * 4 + 1][dl] = (f16)(v.y - (float)h1);
    lh[q * 4 + 2][dl] = h2; ll[q * 4 + 2][dl] = (f16)(v.z - (float)h2);
    lh[q * 4 + 3][dl] = h3; ll[q * 4 + 3][dl] = (f16)(v.w - (float)h3);
  }
  __syncthreads();
  const int rl = threadIdx.x >> 2, seg = threadIdx.x & 3;
  f16* rowo = out + (size_t)(c0 + rl) * KP2 + d0;
#pragma unroll
  for (int j = 0; j < 4; ++j) {
    const int dd = seg * 16 + j * 4;
    f16x4 vh = *(const f16x4*)&lh[rl][dd];
    f16x4 vl = *(const f16x4*)&ll[rl][dd];
    *(f16x4*)&rowo[dd] = vh;
    *(f16x4*)&rowo[768 + dd] = vl;
  }
}

// ---------- BK=32, 2-blocks/CU, 1-barrier/K-tile MFMA GEMM + fused top-4 ----------
// Logical K' = 2304 over NT=72 tiles of 32: A limbs [Xh|Xh|Xl], B limbs [Rh|Rl|Rh].
__global__ __launch_bounds__(512, 4)
void mfma32_topk_kernel(const f16* __restrict__ A2, const f16* __restrict__ B2,
                        const float* __restrict__ r2g,
                        float* __restrict__ pscore, int* __restrict__ pidx) {
  // GEMM LDS: dbuf d at d*32768; within dbuf: A @0 (16 KB), B @16384 (16 KB).
  // Region: 256 rows x 32 K-cols f16 (64 B rows); 16B slot swizzle: seg ^= (row>>1)&3.
  // Epilogue reuses smem: 8 waves x [32][66] f32 = 67584 B.
  __shared__ __align__(16) char smem[67584];
  const int tid  = threadIdx.x;
  const int lane = tid & 63, wid = tid >> 6;
  const int wm = wid >> 2, wn = wid & 3;
  const int ln15 = lane & 15, g4 = lane >> 4;

  // supertile XCD mapping: XCD (flat&7) owns bx in [8x, 8x+8), all by
  const int flat = (int)blockIdx.x;
  const int jj = flat >> 3;
  const int bx = (flat & 7) * 8 + (jj & 7);  // 0..63
  const int by = jj >> 3;                    // 0..7
  const int m0 = by * BM, n0 = bx * BN;

  // ---- staging: 2 gl_lds(16B) per thread per matrix per K-tile ----
  // LDS slot s: row = s>>2, seg = s&3 ; global seg' = seg ^ ((s>>3)&3)
  const int s0 = tid, s1 = tid + 512;
  const int r0 = s0 >> 2, r1 = s1 >> 2;
  const int c0b = (((s0 & 3) ^ ((s0 >> 3) & 3)) << 4);
  const int c1b = (((s1 & 3) ^ ((s1 >> 3) & 3)) << 4);
  const char* gA0 = (const char*)(A2 + (size_t)(m0 + r0) * KP2) + c0b;
  const char* gA1 = (const char*)(A2 + (size_t)(m0 + r1) * KP2) + c1b;
  const char* gB0 = (const char*)(B2 + (size_t)(n0 + r0) * KP2) + c0b;
  const char* gB1 = (const char*)(B2 + (size_t)(n0 + r1) * KP2) + c1b;
  const int l0 = s0 * 16, l1 = s1 * 16;

#define STAGE_A(sdb, kbyte)                                      \
  { gl_lds16(gA0 + (kbyte), smem + (sdb) + l0);                  \
    gl_lds16(gA1 + (kbyte), smem + (sdb) + l1); }
#define STAGE_B(sdb, kbyte)                                      \
  { gl_lds16(gB0 + (kbyte), smem + (sdb) + 16384 + l0);          \
    gl_lds16(gB1 + (kbyte), smem + (sdb) + 16384 + l1); }

  // ---- fragment LDS offsets (K-invariant): lane reads global seg g4 of its row ----
  const int cswz = ((g4 ^ ((ln15 >> 1) & 3)) << 4);
  int offA[8], offB[4];
#pragma unroll
  for (int mi = 0; mi < 8; ++mi) offA[mi] = (wm * 128 + mi * 16 + ln15) * 64 + cswz;
#pragma unroll
  for (int ni = 0; ni < 4; ++ni) offB[ni] = 16384 + (wn * 64 + ni * 16 + ln15) * 64 + cswz;

  f32x4 acc[8][4] = {};

  // prologue: stage tile 0 into dbuf0 (4 loads)
  STAGE_A(0, 0);
  STAGE_B(0, 0);

  for (int kt = 0; kt < NT; ++kt) {
    const int dbuf = (kt & 1) << 15;
    const int sdb  = ((kt + 1) & 1) << 15;
    const int ktn = (kt + 1 < NT) ? kt + 1 : NT - 1;   // tail: restage last (harmless)
    const int tA = ktn < 24 ? ktn : ktn - 24;          // [Xh|Xh|Xl]
    const int tB = ktn < 48 ? ktn : ktn - 48;          // [Rh|Rl|Rh]
    const int kbA = tA * 64, kbB = tB * 64;

    // one barrier per K-tile: prior tile's reads are lgkm-drained (consumed by
    // MFMA) before any wave reaches this barrier -> staging buf^1 is safe.
    asm volatile("s_barrier" ::: "memory");
    STAGE_A(sdb, kbA);
    STAGE_B(sdb, kbB);
    // counted wait: 8 outstanding (4 old + 4 just issued); wait old 4 only.
    asm volatile("s_waitcnt vmcnt(4)" ::: "memory");

    f16x8 a[8], b[4];
    // interleave reads so MFMA(0,0) is ready after 2 reads (in-order lgkm)
    a[0] = *(const f16x8*)(smem + dbuf + offA[0]);
    b[0] = *(const f16x8*)(smem + dbuf + offB[0]);
    a[1] = *(const f16x8*)(smem + dbuf + offA[1]);
    b[1] = *(const f16x8*)(smem + dbuf + offB[1]);
    a[2] = *(const f16x8*)(smem + dbuf + offA[2]);
    b[2] = *(const f16x8*)(smem + dbuf + offB[2]);
    a[3] = *(const f16x8*)(smem + dbuf + offA[3]);
    b[3] = *(const f16x8*)(smem + dbuf + offB[3]);
    a[4] = *(const f16x8*)(smem + dbuf + offA[4]);
    a[5] = *(const f16x8*)(smem + dbuf + offA[5]);
    a[6] = *(const f16x8*)(smem + dbuf + offA[6]);
    a[7] = *(const f16x8*)(smem + dbuf + offA[7]);

    __builtin_amdgcn_s_setprio(1);
#pragma unroll
    for (int mi = 0; mi < 8; ++mi)
#pragma unroll
      for (int ni = 0; ni < 4; ++ni)
        acc[mi][ni] = __builtin_amdgcn_mfma_f32_16x16x32_f16(a[mi], b[ni], acc[mi][ni], 0, 0, 0);
    __builtin_amdgcn_s_setprio(0);
  }

  // drain tail stages; then LDS is ours for the epilogue
  asm volatile("s_waitcnt vmcnt(0)" ::: "memory");
  __syncthreads();

  // ---- epilogue: wave-private transpose -> per-row top-4 over 64-col stripe ----
  float rv[4];
#pragma unroll
  for (int ni = 0; ni < 4; ++ni) rv[ni] = r2g[n0 + wn * 64 + ni * 16 + ln15];
  float* sw = (float*)smem + wid * 2112;   // [32][66] f32, wave-private
  const int rr = lane >> 1, hh = lane & 1;
#pragma unroll
  for (int P = 0; P < 4; ++P) {
#pragma unroll
    for (int mh = 0; mh < 2; ++mh)
#pragma unroll
      for (int ni = 0; ni < 4; ++ni)
#pragma unroll
        for (int r = 0; r < 4; ++r) {
          const int row_l = mh * 16 + g4 * 4 + r;   // C/D: col=lane&15, row=(lane>>4)*4+reg
          sw[row_l * 66 + ni * 16 + ln15] = rv[ni] - 2.0f * acc[2 * P + mh][ni][r];
        }
    asm volatile("s_waitcnt lgkmcnt(0)" ::: "memory");
    __builtin_amdgcn_sched_barrier(0);
    float s[4]  = {1e30f, 1e30f, 1e30f, 1e30f};
    int   id[4] = {0x7fffffff, 0x7fffffff, 0x7fffffff, 0x7fffffff};
    const float* rowp = sw + rr * 66 + hh * 32;
    const int cb = n0 + wn * 64 + hh * 32;
#pragma unroll
    for (int j = 0; j < 16; ++j) {
      const float2 v = *(const float2*)(rowp + j * 2);
      insert4(s, id, v.x, cb + j * 2);
      insert4(s, id, v.y, cb + j * 2 + 1);
    }
    float os[4]; int oid[4];
#pragma unroll
    for (int j = 0; j < 4; ++j) { os[j] = __shfl_xor(s[j], 1); oid[j] = __shfl_xor(id[j], 1); }
    merge_top4(s, id, os, oid);
    if (hh == 0) {
      const int q = m0 + wm * 128 + P * 32 + rr;
      const int base = (q * NL + bx * 4 + wn) * 4;
#pragma unroll
      for (int j = 0; j < 4; ++j) { pscore[base + j] = s[j]; pidx[base + j] = id[j]; }
    }
    asm volatile("s_waitcnt lgkmcnt(0)" ::: "memory");
  }
#undef STAGE_A
#undef STAGE_B
}

// ---------- merge NLISTS partial lists per query -> final 4 indices ----------
template <int NLISTS>
__global__ __launch_bounds__(64)
void select_kernel(const float* __restrict__ pscore, const int* __restrict__ pidx,
                   int* __restrict__ final4) {
  const int t = blockIdx.x, lane = threadIdx.x;
  constexpr int LPL = NLISTS / 64;
  float s[4]  = {1e30f, 1e30f, 1e30f, 1e30f};
  int   id[4] = {0x7fffffff, 0x7fffffff, 0x7fffffff, 0x7fffffff};
#pragma unroll
  for (int li = 0; li < LPL; ++li) {
    const int base = (t * NLISTS + lane * LPL + li) * 4;
    const float4 sv = *(const float4*)&pscore[base];
    const int4   iv = *(const int4*)&pidx[base];
    float os[4] = {sv.x, sv.y, sv.z, sv.w};
    int  oid[4] = {iv.x, iv.y, iv.z, iv.w};
    merge_top4(s, id, os, oid);
  }
#pragma unroll
  for (int mask = 1; mask < 64; mask <<= 1) {
    float os[4]; int oid[4];
#pragma unroll
    for (int j = 0; j < 4; ++j) {
      os[j]  = __shfl_xor(s[j], mask);
      oid[j] = __shfl_xor(id[j], mask);
    }
    merge_top4(s, id, os, oid);
  }
  if (lane == 0) {
    int4 o; o.x = id[0]; o.y = id[1]; o.z = id[2]; o.w = id[3];
    *(int4*)&final4[t * 4] = o;
  }
}

// ---------- gather 4 neighbors, average, write [d][T] ----------
__global__ __launch_bounds__(256)
void gather_kernel(const float* __restrict__ R, const int* __restrict__ final4,
                   float* __restrict__ out) {
  __shared__ int ids[64][4];
  const int tx = threadIdx.x & 63, ty = threadIdx.x >> 6;
  const int t0 = blockIdx.x * 64;
  ((int*)ids)[threadIdx.x] = final4[t0 * 4 + threadIdx.x];
  __syncthreads();
  const int d = blockIdx.y * 4 + ty;
  const float* row = R + (size_t)d * N_REF;
  const float sum = row[ids[tx][0]] + row[ids[tx][1]] + row[ids[tx][2]] + row[ids[tx][3]];
  out[(size_t)d * T_Q + t0 + tx] = 0.25f * sum;
}

// ---------- fallback fp32 pipeline (round-1, known correct) ----------
#define FBM 64
#define FBN 256
#define FBK 16
#define FNL (N_REF / FBN)
__global__ __launch_bounds__(256)
void score_topk_kernel(const float* __restrict__ X, const float* __restrict__ R,
                       const float* __restrict__ r2,
                       float* __restrict__ pscore, int* __restrict__ pidx) {
  __shared__ float As[FBK][FBM];
  __shared__ float Bs[FBK][FBN];
  __shared__ float r2s[FBN];
  const int tid = threadIdx.x;
  const int tx = tid & 15, ty = tid >> 4;
  const int m0 = blockIdx.y * FBM;
  const int n0 = blockIdx.x * FBN;
  r2s[tid] = r2[n0 + tid];
  float acc[4][16];
#pragma unroll
  for (int i = 0; i < 4; ++i)
#pragma unroll
    for (int j = 0; j < 16; ++j) acc[i][j] = 0.f;
  for (int k0 = 0; k0 < DIM; k0 += FBK) {
    {
      const int k = tid >> 4, m4 = tid & 15;
      const float4 av = *(const float4*)&X[(size_t)(k0 + k) * T_Q + m0 + m4 * 4];
      *(float4*)&As[k][m4 * 4] = av;
    }
#pragma unroll
    for (int i = 0; i < 4; ++i) {
      const int idx4 = tid + i * 256;
      const int k = idx4 >> 6, n4 = idx4 & 63;
      const float4 bv = *(const float4*)&R[(size_t)(k0 + k) * N_REF + n0 + n4 * 4];
      *(float4*)&Bs[k][n4 * 4] = bv;
    }
    __syncthreads();
#pragma unroll
    for (int k = 0; k < FBK; ++k) {
      float av[4], bv[16];
      *(float4*)av = *(const float4*)&As[k][ty * 4];
#pragma unroll
      for (int c = 0; c < 4; ++c)
        *(float4*)&bv[c * 4] = *(const float4*)&Bs[k][tx * 4 + c * 64];
#pragma unroll
      for (int mi = 0; mi < 4; ++mi)
#pragma unroll
        for (int ni = 0; ni < 16; ++ni) acc[mi][ni] += av[mi] * bv[ni];
    }
    __syncthreads();
  }
#pragma unroll
  for (int mi = 0; mi < 4; ++mi) {
    float s[4]  = {1e30f, 1e30f, 1e30f, 1e30f};
    int   id[4] = {0x7fffffff, 0x7fffffff, 0x7fffffff, 0x7fffffff};
#pragma unroll
    for (int c = 0; c < 4; ++c)
#pragma unroll
      for (int j = 0; j < 4; ++j) {
        const int nl = tx * 4 + c * 64 + j;
        const float sc = r2s[nl] - 2.0f * acc[mi][c * 4 + j];
        insert4(s, id, sc, n0 + nl);
      }
#pragma unroll
    for (int mask = 1; mask < 16; mask <<= 1) {
      float os[4]; int oid[4];
#pragma unroll
      for (int j = 0; j < 4; ++j) {
        os[j]  = __shfl_xor(s[j], mask);
        oid[j] = __shfl_xor(id[j], mask);
      }
      merge_top4(s, id, os, oid);
    }
    if (tx == 0) {
      const int t = m0 + ty * 4 + mi;
      const int base = (t * FNL + (int)blockIdx.x) * 4;
#pragma unroll
      for (int j = 0; j < 4; ++j) { pscore[base + j] = s[j]; pidx[base + j] = id[j]; }
    }
  }
}

extern "C" void kernel_launch(void* const* d_in, const int* in_sizes, int n_in,
                              void* d_out, int out_size, void* d_ws, size_t ws_size,
                              hipStream_t stream) {
  const float* X = (const float*)d_in[0];   // [768][2048]
  const float* R = (const float*)d_in[1];   // [768][16384]
  float* out = (float*)d_out;               // [768][2048]

  const size_t szA2 = (size_t)T_Q * KP2 * sizeof(f16);       // 6,291,456
  const size_t szB2 = (size_t)N_REF * KP2 * sizeof(f16);     // 50,331,648
  const size_t szr2 = (size_t)N_REF * sizeof(float);         // 65,536
  const size_t szPS = (size_t)T_Q * NL * 4 * sizeof(float);  // 8,388,608
  const size_t need = szA2 + szB2 + szr2 + 2 * szPS + (size_t)T_Q * 4 * sizeof(int);

  if (ws_size >= need) {
    char* w = (char*)d_ws;
    f16* A2 = (f16*)w;            w += szA2;
    f16* B2 = (f16*)w;            w += szB2;
    float* r2     = (float*)w;    w += szr2;
    float* pscore = (float*)w;    w += szPS;
    int*   pidx   = (int*)w;      w += szPS;
    int*   final4 = (int*)w;

    hipLaunchKernelGGL(r2_kernel, dim3(N_REF / 64), dim3(256), 0, stream, R, r2);
    hipLaunchKernelGGL(tsplit_kernel, dim3(T_Q / 64, DIM / 64), dim3(256), 0, stream,
                       X, A2, T_Q);
    hipLaunchKernelGGL(tsplit_kernel, dim3(N_REF / 64, DIM / 64), dim3(256), 0, stream,
                       R, B2, N_REF);
    hipLaunchKernelGGL(mfma32_topk_kernel, dim3((N_REF / BN) * (T_Q / BM)), dim3(512), 0, stream,
                       A2, B2, r2, pscore, pidx);
    hipLaunchKernelGGL((select_kernel<NL>), dim3(T_Q), dim3(64), 0, stream,
                       pscore, pidx, final4);
    hipLaunchKernelGGL(gather_kernel, dim3(T_Q / 64, DIM / 4), dim3(256), 0, stream,
                       R, final4, out);
  } else {
    // fallback: fp32 pipeline (~4.2 MB ws)
    char* w = (char*)d_ws;
    float* r2     = (float*)w;  w += szr2;
    float* pscore = (float*)w;  w += (size_t)T_Q * FNL * 4 * sizeof(float);
    int*   pidx   = (int*)w;    w += (size_t)T_Q * FNL * 4 * sizeof(int);
    int*   final4 = (int*)w;

    hipLaunchKernelGGL(r2_kernel, dim3(N_REF / 64), dim3(256), 0, stream, R, r2);
    hipLaunchKernelGGL(score_topk_kernel, dim3(N_REF / FBN, T_Q / FBM), dim3(256), 0, stream,
                       X, R, r2, pscore, pidx);
    hipLaunchKernelGGL((select_kernel<FNL>), dim3(T_Q), dim3(64), 0, stream,
                       pscore, pidx, final4);
    hipLaunchKernelGGL(gather_kernel, dim3(T_Q / 64, DIM / 4), dim3(256), 0, stream,
                       R, final4, out);
  }
}

// Round 7
// 261.790 us; speedup vs baseline: 5.1668x; 5.1668x over previous
//
#include <hip/hip_runtime.h>
#include <stdint.h>

#define T_Q   2048
#define N_REF 16384
#define DIM   768
#define KP2   1536        // packed K cols: [hi | lo]
#define NT    72          // logical K' = 2304 = 72 tiles of 32
#define BM    256
#define BN    256
#define NL    256         // partial top-4 lists per query

using f16   = _Float16;
using f16x4 = __attribute__((ext_vector_type(4))) _Float16;
using f16x8 = __attribute__((ext_vector_type(8))) _Float16;
using f32x4 = __attribute__((ext_vector_type(4))) float;

// ---------- lexicographic top-4 helpers (static indices only) ----------
__device__ __forceinline__ bool lex_less(float sa, int ia, float sb, int ib) {
  return (sa < sb) || (sa == sb && ia < ib);
}
#define CE_PAIR(s0, i0, s1, i1)                                        \
  { if (lex_less(s1, i1, s0, i0)) { float _ts = s0; s0 = s1; s1 = _ts; \
                                    int _ti = i0; i0 = i1; i1 = _ti; } }
#define PICKMIN(as, ai, bs, bi, rs, ri)                   \
  { if (lex_less(bs, bi, as, ai)) { rs = bs; ri = bi; }   \
    else                          { rs = as; ri = ai; } }

__device__ __forceinline__ void insert4(float s[4], int id[4], float sc, int n) {
  if (lex_less(sc, n, s[3], id[3])) {
    s[3] = sc; id[3] = n;
    CE_PAIR(s[2], id[2], s[3], id[3]);
    CE_PAIR(s[1], id[1], s[2], id[2]);
    CE_PAIR(s[0], id[0], s[1], id[1]);
  }
}
__device__ __forceinline__ void merge_top4(float s[4], int id[4],
                                           const float os[4], const int oid[4]) {
  float l0, l1, l2, l3; int j0, j1, j2, j3;
  PICKMIN(s[0], id[0], os[3], oid[3], l0, j0);
  PICKMIN(s[1], id[1], os[2], oid[2], l1, j1);
  PICKMIN(s[2], id[2], os[1], oid[1], l2, j2);
  PICKMIN(s[3], id[3], os[0], oid[0], l3, j3);
  CE_PAIR(l0, j0, l2, j2);
  CE_PAIR(l1, j1, l3, j3);
  CE_PAIR(l0, j0, l1, j1);
  CE_PAIR(l2, j2, l3, j3);
  s[0] = l0; s[1] = l1; s[2] = l2; s[3] = l3;
  id[0] = j0; id[1] = j1; id[2] = j2; id[3] = j3;
}

__device__ __forceinline__ void gl_lds16(const void* g, void* l) {
  __builtin_amdgcn_global_load_lds((const __attribute__((address_space(1))) uint32_t*)g,
                                   (__attribute__((address_space(3))) uint32_t*)l, 16, 0, 0);
}

// ---------- r2[n] = ||ref_n||^2 (fp32 exact) ----------
__global__ __launch_bounds__(256)
void r2_kernel(const float* __restrict__ R, float* __restrict__ r2) {
  __shared__ float red[256];
  const int lane = threadIdx.x & 63;
  const int dg   = threadIdx.x >> 6;
  const int n    = blockIdx.x * 64 + lane;
  float acc = 0.f;
  const int d0 = dg * (DIM / 4), d1 = d0 + (DIM / 4);
  for (int d = d0; d < d1; ++d) {
    float v = R[(size_t)d * N_REF + n];
    acc += v * v;
  }
  red[threadIdx.x] = acc;
  __syncthreads();
  if (threadIdx.x < 64)
    r2[n] = red[lane] + red[lane + 64] + red[lane + 128] + red[lane + 192];
}

// ---------- transpose + f16 hi/lo split: in[D][W] -> out[W][1536] = [hi | lo] ----------
__global__ __launch_bounds__(256)
void tsplit_kernel(const float* __restrict__ in, f16* __restrict__ out, int W) {
  __shared__ f16 lh[64][66], ll[64][66];
  const int c0 = blockIdx.x * 64, d0 = blockIdx.y * 64;
  const int q = threadIdx.x & 15, p = threadIdx.x >> 4;
#pragma unroll
  for (int i = 0; i < 4; ++i) {
    const int dl = p + i * 16;
    const float4 v = *(const float4*)&in[(size_t)(d0 + dl) * W + c0 + q * 4];
    const f16 h0 = (f16)v.x, h1 = (f16)v.y, h2 = (f16)v.z, h3 = (f16)v.w;
    lh[q * 4 + 0][dl] = h0; ll[q * 4 + 0][dl] = (f16)(v.x - (float)h0);
    lh[q * 4 + 1][dl] = h1; ll[q * 4 + 1][dl] = (f16)(v.y - (float)h1);
    lh[q * 4 + 2][dl] = h2; ll[q * 4 + 2][dl] = (f16)(v.z - (float)h2);
    lh[q * 4 + 3][dl] = h3; ll[q * 4 + 3][dl] = (f16)(v.w - (float)h3);
  }
  __syncthreads();
  const int rl = threadIdx.x >> 2, seg = threadIdx.x & 3;
  f16* rowo = out + (size_t)(c0 + rl) * KP2 + d0;
#pragma unroll
  for (int j = 0; j < 4; ++j) {
    const int dd = seg * 16 + j * 4;
    f16x4 vh = *(const f16x4*)&lh[rl][dd];
    f16x4 vl = *(const f16x4*)&ll[rl][dd];
    *(f16x4*)&rowo[dd] = vh;
    *(f16x4*)&rowo[768 + dd] = vl;
  }
}

// ---------- BK=32, 4-buffer 2-deep pipeline MFMA GEMM + fused top-4 ----------
// Logical K' = 2304 over NT=72 tiles of 32: A limbs [Xh|Xh|Xl], B limbs [Rh|Rl|Rh].
// Sync discipline (race-fixed vs r5/r6): per tile {STAGE(kt+2) -> vmcnt(8) ->
// s_barrier -> reads -> MFMA}. Counted vmcnt BEFORE the barrier makes each
// wave's load-completion collective; vmcnt after the barrier (r5/r6) is a
// cross-wave race (vmcnt is per-wave) that r5 masked via spill slowness.
__global__ __launch_bounds__(512, 2)
void mfma32_topk_kernel(const f16* __restrict__ A2, const f16* __restrict__ B2,
                        const float* __restrict__ r2g,
                        float* __restrict__ pscore, int* __restrict__ pidx) {
  // LDS: 4 rotating bufs, buf q at q*32768: A @0 (16 KB), B @16384 (16 KB).
  // Region: 256 rows x 32 K-cols f16 (64 B rows); 16B slot swizzle: seg ^= (row>>1)&3.
  // Epilogue reuses [0, 67584).
  __shared__ __align__(16) char smem[131072];
  const int tid  = threadIdx.x;
  const int lane = tid & 63, wid = tid >> 6;
  const int wm = wid >> 2, wn = wid & 3;
  const int ln15 = lane & 15, g4 = lane >> 4;

  // supertile XCD mapping: XCD (flat&7) owns bx in [8x, 8x+8), all by
  const int flat = (int)blockIdx.x;
  const int jj = flat >> 3;
  const int bx = (flat & 7) * 8 + (jj & 7);  // 0..63
  const int by = jj >> 3;                    // 0..7
  const int m0 = by * BM, n0 = bx * BN;

  // ---- staging: 2 gl_lds(16B) per thread per matrix per K-tile ----
  // LDS slot s: row = s>>2, seg = s&3 ; global seg' = seg ^ ((s>>3)&3)
  const int s0 = tid, s1 = tid + 512;
  const int r0 = s0 >> 2, r1 = s1 >> 2;
  const int c0b = (((s0 & 3) ^ ((s0 >> 3) & 3)) << 4);
  const int c1b = (((s1 & 3) ^ ((s1 >> 3) & 3)) << 4);
  const char* gA0 = (const char*)(A2 + (size_t)(m0 + r0) * KP2) + c0b;
  const char* gA1 = (const char*)(A2 + (size_t)(m0 + r1) * KP2) + c1b;
  const char* gB0 = (const char*)(B2 + (size_t)(n0 + r0) * KP2) + c0b;
  const char* gB1 = (const char*)(B2 + (size_t)(n0 + r1) * KP2) + c1b;
  const int l0 = s0 * 16, l1 = s1 * 16;

#define STAGE_A(sdb, kbyte)                                      \
  { gl_lds16(gA0 + (kbyte), smem + (sdb) + l0);                  \
    gl_lds16(gA1 + (kbyte), smem + (sdb) + l1); }
#define STAGE_B(sdb, kbyte)                                      \
  { gl_lds16(gB0 + (kbyte), smem + (sdb) + 16384 + l0);          \
    gl_lds16(gB1 + (kbyte), smem + (sdb) + 16384 + l1); }

  // ---- fragment LDS offsets (K-invariant): lane reads global seg g4 of its row ----
  const int cswz = ((g4 ^ ((ln15 >> 1) & 3)) << 4);
  int offA[8], offB[4];
#pragma unroll
  for (int mi = 0; mi < 8; ++mi) offA[mi] = (wm * 128 + mi * 16 + ln15) * 64 + cswz;
#pragma unroll
  for (int ni = 0; ni < 4; ++ni) offB[ni] = 16384 + (wn * 64 + ni * 16 + ln15) * 64 + cswz;

  f32x4 acc[8][4] = {};

  // prologue: stage tile 0 -> buf0, tile 1 -> buf1 (8 loads outstanding)
  STAGE_A(0, 0);
  STAGE_B(0, 0);
  STAGE_A(32768, 64);   // tile 1: tA = tB = 1 -> kbyte 64
  STAGE_B(32768, 64);

  for (int kt = 0; kt < NT; ++kt) {
    const int dbuf = (kt & 3) << 15;
    const int sdb  = ((kt + 2) & 3) << 15;
    const int ktn = (kt + 2 < NT) ? kt + 2 : NT - 1;   // tail: restage last (never read)
    const int tA = ktn < 24 ? ktn : ktn - 24;          // [Xh|Xh|Xl]
    const int tB = ktn < 48 ? ktn : ktn - 48;          // [Rh|Rl|Rh]

    // issue next+2 tile loads (buffer was last read at kt-2; drained before the
    // last barrier every wave crossed)
    STAGE_A(sdb, tA * 64);
    STAGE_B(sdb, tB * 64);
    // retire THIS tile's 4 loads (12 -> 8 outstanding), then collective barrier
    asm volatile("s_waitcnt vmcnt(8)" ::: "memory");
    asm volatile("s_barrier" ::: "memory");

    f16x8 a[8], b[4];
    // interleave reads so MFMA(0,0) is ready after 2 reads (in-order lgkm)
    a[0] = *(const f16x8*)(smem + dbuf + offA[0]);
    b[0] = *(const f16x8*)(smem + dbuf + offB[0]);
    a[1] = *(const f16x8*)(smem + dbuf + offA[1]);
    b[1] = *(const f16x8*)(smem + dbuf + offB[1]);
    a[2] = *(const f16x8*)(smem + dbuf + offA[2]);
    b[2] = *(const f16x8*)(smem + dbuf + offB[2]);
    a[3] = *(const f16x8*)(smem + dbuf + offA[3]);
    b[3] = *(const f16x8*)(smem + dbuf + offB[3]);
    a[4] = *(const f16x8*)(smem + dbuf + offA[4]);
    a[5] = *(const f16x8*)(smem + dbuf + offA[5]);
    a[6] = *(const f16x8*)(smem + dbuf + offA[6]);
    a[7] = *(const f16x8*)(smem + dbuf + offA[7]);

    __builtin_amdgcn_s_setprio(1);
#pragma unroll
    for (int mi = 0; mi < 8; ++mi)
#pragma unroll
      for (int ni = 0; ni < 4; ++ni)
        acc[mi][ni] = __builtin_amdgcn_mfma_f32_16x16x32_f16(a[mi], b[ni], acc[mi][ni], 0, 0, 0);
    __builtin_amdgcn_s_setprio(0);
  }

  // drain tail junk stages; then LDS is ours for the epilogue
  asm volatile("s_waitcnt vmcnt(0)" ::: "memory");
  __syncthreads();

  // ---- epilogue: wave-private transpose -> per-row top-4 over 64-col stripe ----
  float rv[4];
#pragma unroll
  for (int ni = 0; ni < 4; ++ni) rv[ni] = r2g[n0 + wn * 64 + ni * 16 + ln15];
  float* sw = (float*)smem + wid * 2112;   // [32][66] f32, wave-private
  const int rr = lane >> 1, hh = lane & 1;
#pragma unroll
  for (int P = 0; P < 4; ++P) {
#pragma unroll
    for (int mh = 0; mh < 2; ++mh)
#pragma unroll
      for (int ni = 0; ni < 4; ++ni)
#pragma unroll
        for (int r = 0; r < 4; ++r) {
          const int row_l = mh * 16 + g4 * 4 + r;   // C/D: col=lane&15, row=(lane>>4)*4+reg
          sw[row_l * 66 + ni * 16 + ln15] = rv[ni] - 2.0f * acc[2 * P + mh][ni][r];
        }
    asm volatile("s_waitcnt lgkmcnt(0)" ::: "memory");
    __builtin_amdgcn_sched_barrier(0);
    float s[4]  = {1e30f, 1e30f, 1e30f, 1e30f};
    int   id[4] = {0x7fffffff, 0x7fffffff, 0x7fffffff, 0x7fffffff};
    const float* rowp = sw + rr * 66 + hh * 32;
    const int cb = n0 + wn * 64 + hh * 32;
#pragma unroll
    for (int j = 0; j < 16; ++j) {
      const float2 v = *(const float2*)(rowp + j * 2);
      insert4(s, id, v.x, cb + j * 2);
      insert4(s, id, v.y, cb + j * 2 + 1);
    }
    float os[4]; int oid[4];
#pragma unroll
    for (int j = 0; j < 4; ++j) { os[j] = __shfl_xor(s[j], 1); oid[j] = __shfl_xor(id[j], 1); }
    merge_top4(s, id, os, oid);
    if (hh == 0) {
      const int q = m0 + wm * 128 + P * 32 + rr;
      const int base = (q * NL + bx * 4 + wn) * 4;
#pragma unroll
      for (int j = 0; j < 4; ++j) { pscore[base + j] = s[j]; pidx[base + j] = id[j]; }
    }
    asm volatile("s_waitcnt lgkmcnt(0)" ::: "memory");
  }
#undef STAGE_A
#undef STAGE_B
}

// ---------- merge NLISTS partial lists per query -> final 4 indices ----------
template <int NLISTS>
__global__ __launch_bounds__(64)
void select_kernel(const float* __restrict__ pscore, const int* __restrict__ pidx,
                   int* __restrict__ final4) {
  const int t = blockIdx.x, lane = threadIdx.x;
  constexpr int LPL = NLISTS / 64;
  float s[4]  = {1e30f, 1e30f, 1e30f, 1e30f};
  int   id[4] = {0x7fffffff, 0x7fffffff, 0x7fffffff, 0x7fffffff};
#pragma unroll
  for (int li = 0; li < LPL; ++li) {
    const int base = (t * NLISTS + lane * LPL + li) * 4;
    const float4 sv = *(const float4*)&pscore[base];
    const int4   iv = *(const int4*)&pidx[base];
    float os[4] = {sv.x, sv.y, sv.z, sv.w};
    int  oid[4] = {iv.x, iv.y, iv.z, iv.w};
    merge_top4(s, id, os, oid);
  }
#pragma unroll
  for (int mask = 1; mask < 64; mask <<= 1) {
    float os[4]; int oid[4];
#pragma unroll
    for (int j = 0; j < 4; ++j) {
      os[j]  = __shfl_xor(s[j], mask);
      oid[j] = __shfl_xor(id[j], mask);
    }
    merge_top4(s, id, os, oid);
  }
  if (lane == 0) {
    int4 o; o.x = id[0]; o.y = id[1]; o.z = id[2]; o.w = id[3];
    *(int4*)&final4[t * 4] = o;
  }
}

// ---------- gather 4 neighbors, average, write [d][T] ----------
__global__ __launch_bounds__(256)
void gather_kernel(const float* __restrict__ R, const int* __restrict__ final4,
                   float* __restrict__ out) {
  __shared__ int ids[64][4];
  const int tx = threadIdx.x & 63, ty = threadIdx.x >> 6;
  const int t0 = blockIdx.x * 64;
  ((int*)ids)[threadIdx.x] = final4[t0 * 4 + threadIdx.x];
  __syncthreads();
  const int d = blockIdx.y * 4 + ty;
  const float* row = R + (size_t)d * N_REF;
  const float sum = row[ids[tx][0]] + row[ids[tx][1]] + row[ids[tx][2]] + row[ids[tx][3]];
  out[(size_t)d * T_Q + t0 + tx] = 0.25f * sum;
}

// ---------- fallback fp32 pipeline (round-1, known correct) ----------
#define FBM 64
#define FBN 256
#define FBK 16
#define FNL (N_REF / FBN)
__global__ __launch_bounds__(256)
void score_topk_kernel(const float* __restrict__ X, const float* __restrict__ R,
                       const float* __restrict__ r2,
                       float* __restrict__ pscore, int* __restrict__ pidx) {
  __shared__ float As[FBK][FBM];
  __shared__ float Bs[FBK][FBN];
  __shared__ float r2s[FBN];
  const int tid = threadIdx.x;
  const int tx = tid & 15, ty = tid >> 4;
  const int m0 = blockIdx.y * FBM;
  const int n0 = blockIdx.x * FBN;
  r2s[tid] = r2[n0 + tid];
  float acc[4][16];
#pragma unroll
  for (int i = 0; i < 4; ++i)
#pragma unroll
    for (int j = 0; j < 16; ++j) acc[i][j] = 0.f;
  for (int k0 = 0; k0 < DIM; k0 += FBK) {
    {
      const int k = tid >> 4, m4 = tid & 15;
      const float4 av = *(const float4*)&X[(size_t)(k0 + k) * T_Q + m0 + m4 * 4];
      *(float4*)&As[k][m4 * 4] = av;
    }
#pragma unroll
    for (int i = 0; i < 4; ++i) {
      const int idx4 = tid + i * 256;
      const int k = idx4 >> 6, n4 = idx4 & 63;
      const float4 bv = *(const float4*)&R[(size_t)(k0 + k) * N_REF + n0 + n4 * 4];
      *(float4*)&Bs[k][n4 * 4] = bv;
    }
    __syncthreads();
#pragma unroll
    for (int k = 0; k < FBK; ++k) {
      float av[4], bv[16];
      *(float4*)av = *(const float4*)&As[k][ty * 4];
#pragma unroll
      for (int c = 0; c < 4; ++c)
        *(float4*)&bv[c * 4] = *(const float4*)&Bs[k][tx * 4 + c * 64];
#pragma unroll
      for (int mi = 0; mi < 4; ++mi)
#pragma unroll
        for (int ni = 0; ni < 16; ++ni) acc[mi][ni] += av[mi] * bv[ni];
    }
    __syncthreads();
  }
#pragma unroll
  for (int mi = 0; mi < 4; ++mi) {
    float s[4]  = {1e30f, 1e30f, 1e30f, 1e30f};
    int   id[4] = {0x7fffffff, 0x7fffffff, 0x7fffffff, 0x7fffffff};
#pragma unroll
    for (int c = 0; c < 4; ++c)
#pragma unroll
      for (int j = 0; j < 4; ++j) {
        const int nl = tx * 4 + c * 64 + j;
        const float sc = r2s[nl] - 2.0f * acc[mi][c * 4 + j];
        insert4(s, id, sc, n0 + nl);
      }
#pragma unroll
    for (int mask = 1; mask < 16; mask <<= 1) {
      float os[4]; int oid[4];
#pragma unroll
      for (int j = 0; j < 4; ++j) {
        os[j]  = __shfl_xor(s[j], mask);
        oid[j] = __shfl_xor(id[j], mask);
      }
      merge_top4(s, id, os, oid);
    }
    if (tx == 0) {
      const int t = m0 + ty * 4 + mi;
      const int base = (t * FNL + (int)blockIdx.x) * 4;
#pragma unroll
      for (int j = 0; j < 4; ++j) { pscore[base + j] = s[j]; pidx[base + j] = id[j]; }
    }
  }
}

extern "C" void kernel_launch(void* const* d_in, const int* in_sizes, int n_in,
                              void* d_out, int out_size, void* d_ws, size_t ws_size,
                              hipStream_t stream) {
  const float* X = (const float*)d_in[0];   // [768][2048]
  const float* R = (const float*)d_in[1];   // [768][16384]
  float* out = (float*)d_out;               // [768][2048]

  const size_t szA2 = (size_t)T_Q * KP2 * sizeof(f16);       // 6,291,456
  const size_t szB2 = (size_t)N_REF * KP2 * sizeof(f16);     // 50,331,648
  const size_t szr2 = (size_t)N_REF * sizeof(float);         // 65,536
  const size_t szPS = (size_t)T_Q * NL * 4 * sizeof(float);  // 8,388,608
  const size_t need = szA2 + szB2 + szr2 + 2 * szPS + (size_t)T_Q * 4 * sizeof(int);

  if (ws_size >= need) {
    char* w = (char*)d_ws;
    f16* A2 = (f16*)w;            w += szA2;
    f16* B2 = (f16*)w;            w += szB2;
    float* r2     = (float*)w;    w += szr2;
    float* pscore = (float*)w;    w += szPS;
    int*   pidx   = (int*)w;      w += szPS;
    int*   final4 = (int*)w;

    hipLaunchKernelGGL(r2_kernel, dim3(N_REF / 64), dim3(256), 0, stream, R, r2);
    hipLaunchKernelGGL(tsplit_kernel, dim3(T_Q / 64, DIM / 64), dim3(256), 0, stream,
                       X, A2, T_Q);
    hipLaunchKernelGGL(tsplit_kernel, dim3(N_REF / 64, DIM / 64), dim3(256), 0, stream,
                       R, B2, N_REF);
    hipLaunchKernelGGL(mfma32_topk_kernel, dim3((N_REF / BN) * (T_Q / BM)), dim3(512), 0, stream,
                       A2, B2, r2, pscore, pidx);
    hipLaunchKernelGGL((select_kernel<NL>), dim3(T_Q), dim3(64), 0, stream,
                       pscore, pidx, final4);
    hipLaunchKernelGGL(gather_kernel, dim3(T_Q / 64, DIM / 4), dim3(256), 0, stream,
                       R, final4, out);
  } else {
    // fallback: fp32 pipeline (~4.2 MB ws)
    char* w = (char*)d_ws;
    float* r2     = (float*)w;  w += szr2;
    float* pscore = (float*)w;  w += (size_t)T_Q * FNL * 4 * sizeof(float);
    int*   pidx   = (int*)w;    w += (size_t)T_Q * FNL * 4 * sizeof(int);
    int*   final4 = (int*)w;

    hipLaunchKernelGGL(r2_kernel, dim3(N_REF / 64), dim3(256), 0, stream, R, r2);
    hipLaunchKernelGGL(score_topk_kernel, dim3(N_REF / FBN, T_Q / FBM), dim3(256), 0, stream,
                       X, R, r2, pscore, pidx);
    hipLaunchKernelGGL((select_kernel<FNL>), dim3(T_Q), dim3(64), 0, stream,
                       pscore, pidx, final4);
    hipLaunchKernelGGL(gather_kernel, dim3(T_Q / 64, DIM / 4), dim3(256), 0, stream,
                       R, final4, out);
  }
}

// Round 8
// 261.777 us; speedup vs baseline: 5.1670x; 1.0001x over previous
//
#include <hip/hip_runtime.h>
#include <stdint.h>

#define T_Q   2048
#define N_REF 16384
#define DIM   768
#define KP2   1536        // packed K cols: [hi | lo]
#define NT    72          // logical K' = 2304 = 72 tiles of 32
#define BM    256
#define BN    256
#define NL    256         // partial top-4 lists per query

using f16   = _Float16;
using f16x4 = __attribute__((ext_vector_type(4))) _Float16;
using f16x8 = __attribute__((ext_vector_type(8))) _Float16;
using f32x4 = __attribute__((ext_vector_type(4))) float;

// ---------- lexicographic top-4 helpers (static indices only) ----------
__device__ __forceinline__ bool lex_less(float sa, int ia, float sb, int ib) {
  return (sa < sb) || (sa == sb && ia < ib);
}
#define CE_PAIR(s0, i0, s1, i1)                                        \
  { if (lex_less(s1, i1, s0, i0)) { float _ts = s0; s0 = s1; s1 = _ts; \
                                    int _ti = i0; i0 = i1; i1 = _ti; } }
#define PICKMIN(as, ai, bs, bi, rs, ri)                   \
  { if (lex_less(bs, bi, as, ai)) { rs = bs; ri = bi; }   \
    else                          { rs = as; ri = ai; } }

__device__ __forceinline__ void insert4(float s[4], int id[4], float sc, int n) {
  if (lex_less(sc, n, s[3], id[3])) {
    s[3] = sc; id[3] = n;
    CE_PAIR(s[2], id[2], s[3], id[3]);
    CE_PAIR(s[1], id[1], s[2], id[2]);
    CE_PAIR(s[0], id[0], s[1], id[1]);
  }
}
__device__ __forceinline__ void merge_top4(float s[4], int id[4],
                                           const float os[4], const int oid[4]) {
  float l0, l1, l2, l3; int j0, j1, j2, j3;
  PICKMIN(s[0], id[0], os[3], oid[3], l0, j0);
  PICKMIN(s[1], id[1], os[2], oid[2], l1, j1);
  PICKMIN(s[2], id[2], os[1], oid[1], l2, j2);
  PICKMIN(s[3], id[3], os[0], oid[0], l3, j3);
  CE_PAIR(l0, j0, l2, j2);
  CE_PAIR(l1, j1, l3, j3);
  CE_PAIR(l0, j0, l1, j1);
  CE_PAIR(l2, j2, l3, j3);
  s[0] = l0; s[1] = l1; s[2] = l2; s[3] = l3;
  id[0] = j0; id[1] = j1; id[2] = j2; id[3] = j3;
}

__device__ __forceinline__ void gl_lds16(const void* g, void* l) {
  __builtin_amdgcn_global_load_lds((const __attribute__((address_space(1))) uint32_t*)g,
                                   (__attribute__((address_space(3))) uint32_t*)l, 16, 0, 0);
}

// ---------- r2[n] = ||ref_n||^2 (fp32 exact) ----------
__global__ __launch_bounds__(256)
void r2_kernel(const float* __restrict__ R, float* __restrict__ r2) {
  __shared__ float red[256];
  const int lane = threadIdx.x & 63;
  const int dg   = threadIdx.x >> 6;
  const int n    = blockIdx.x * 64 + lane;
  float acc = 0.f;
  const int d0 = dg * (DIM / 4), d1 = d0 + (DIM / 4);
  for (int d = d0; d < d1; ++d) {
    float v = R[(size_t)d * N_REF + n];
    acc += v * v;
  }
  red[threadIdx.x] = acc;
  __syncthreads();
  if (threadIdx.x < 64)
    r2[n] = red[lane] + red[lane + 64] + red[lane + 128] + red[lane + 192];
}

// ---------- transpose + f16 hi/lo split: in[D][W] -> out[W][1536] = [hi | lo] ----------
__global__ __launch_bounds__(256)
void tsplit_kernel(const float* __restrict__ in, f16* __restrict__ out, int W) {
  __shared__ f16 lh[64][66], ll[64][66];
  const int c0 = blockIdx.x * 64, d0 = blockIdx.y * 64;
  const int q = threadIdx.x & 15, p = threadIdx.x >> 4;
#pragma unroll
  for (int i = 0; i < 4; ++i) {
    const int dl = p + i * 16;
    const float4 v = *(const float4*)&in[(size_t)(d0 + dl) * W + c0 + q * 4];
    const f16 h0 = (f16)v.x, h1 = (f16)v.y, h2 = (f16)v.z, h3 = (f16)v.w;
    lh[q * 4 + 0][dl] = h0; ll[q * 4 + 0][dl] = (f16)(v.x - (float)h0);
    lh[q * 4 + 1][dl] = h1; ll[q * 4 + 1][dl] = (f16)(v.y - (float)h1);
    lh[q * 4 + 2][dl] = h2; ll[q * 4 + 2][dl] = (f16)(v.z - (float)h2);
    lh[q * 4 + 3][dl] = h3; ll[q * 4 + 3][dl] = (f16)(v.w - (float)h3);
  }
  __syncthreads();
  const int rl = threadIdx.x >> 2, seg = threadIdx.x & 3;
  f16* rowo = out + (size_t)(c0 + rl) * KP2 + d0;
#pragma unroll
  for (int j = 0; j < 4; ++j) {
    const int dd = seg * 16 + j * 4;
    f16x4 vh = *(const f16x4*)&lh[rl][dd];
    f16x4 vl = *(const f16x4*)&ll[rl][dd];
    *(f16x4*)&rowo[dd] = vh;
    *(f16x4*)&rowo[768 + dd] = vl;
  }
}

// ---------- BK=32, 4-buf depth-2, FINE-PHASE interleaved MFMA GEMM + top-4 ----------
// Logical K' = 2304 over NT=72 tiles of 32: A limbs [Xh|Xh|Xl], B limbs [Rh|Rl|Rh].
// Ledger (round-7 proven): per tile {vmcnt(4) retire this tile's 4 loads ->
// s_barrier -> phases}. Phases spread stages one-per-phase BETWEEN read groups
// and fence each 16-MFMA cluster with lgkmcnt(0)+sched_barrier (m201 T3 form);
// one barrier/tile lets the 2 waves/SIMD anti-phase (read || MFMA cross-wave).
__global__ __launch_bounds__(512, 2)
void mfma32_topk_kernel(const f16* __restrict__ A2, const f16* __restrict__ B2,
                        const float* __restrict__ r2g,
                        float* __restrict__ pscore, int* __restrict__ pidx) {
  // LDS: 4 rotating bufs, buf q at q*32768: A @0 (16 KB), B @16384 (16 KB).
  // Region: 256 rows x 32 K-cols f16 (64 B rows); 16B slot swizzle: slot ^= (row>>1)&3
  // (full 8-bank-quad spread over 8 consecutive rows -> free 2-way).
  __shared__ __align__(16) char smem[131072];
  const int tid  = threadIdx.x;
  const int lane = tid & 63, wid = tid >> 6;
  const int wm = wid >> 2, wn = wid & 3;
  const int ln15 = lane & 15, g4 = lane >> 4;

  // supertile XCD mapping: XCD (flat&7) owns bx in [8x, 8x+8), all by
  const int flat = (int)blockIdx.x;
  const int jj = flat >> 3;
  const int bx = (flat & 7) * 8 + (jj & 7);  // 0..63
  const int by = jj >> 3;                    // 0..7
  const int m0 = by * BM, n0 = bx * BN;

  // ---- staging: 2 gl_lds(16B) per thread per matrix per K-tile ----
  // LDS slot s: row = s>>2, lslot = s&3 ; global slot = lslot ^ ((s>>3)&3)
  const int s0 = tid, s1 = tid + 512;
  const int r0 = s0 >> 2, r1 = s1 >> 2;
  const int c0b = (((s0 & 3) ^ ((s0 >> 3) & 3)) << 4);
  const int c1b = (((s1 & 3) ^ ((s1 >> 3) & 3)) << 4);
  const char* gA0 = (const char*)(A2 + (size_t)(m0 + r0) * KP2) + c0b;
  const char* gA1 = (const char*)(A2 + (size_t)(m0 + r1) * KP2) + c1b;
  const char* gB0 = (const char*)(B2 + (size_t)(n0 + r0) * KP2) + c0b;
  const char* gB1 = (const char*)(B2 + (size_t)(n0 + r1) * KP2) + c1b;
  const int l0 = s0 * 16, l1 = s1 * 16;

#define STAGE_A(sdb, kbyte)                                      \
  { gl_lds16(gA0 + (kbyte), smem + (sdb) + l0);                  \
    gl_lds16(gA1 + (kbyte), smem + (sdb) + l1); }
#define STAGE_B(sdb, kbyte)                                      \
  { gl_lds16(gB0 + (kbyte), smem + (sdb) + 16384 + l0);          \
    gl_lds16(gB1 + (kbyte), smem + (sdb) + 16384 + l1); }

  // ---- fragment LDS offsets (K-invariant): lane reads global slot g4 of its row ----
  const int cswz = ((g4 ^ ((ln15 >> 1) & 3)) << 4);
  int offA[8], offB[4];
#pragma unroll
  for (int mi = 0; mi < 8; ++mi) offA[mi] = (wm * 128 + mi * 16 + ln15) * 64 + cswz;
#pragma unroll
  for (int ni = 0; ni < 4; ++ni) offB[ni] = 16384 + (wn * 64 + ni * 16 + ln15) * 64 + cswz;

  f32x4 acc[8][4] = {};

  // prologue: stage tile 0 -> buf0, tile 1 -> buf1 (8 loads outstanding)
  STAGE_A(0, 0);
  STAGE_B(0, 0);
  STAGE_A(32768, 64);   // tile 1: tA = tB = 1 -> kbyte 64
  STAGE_B(32768, 64);

  for (int kt = 0; kt < NT; ++kt) {
    const int dbuf = (kt & 3) << 15;
    const int sdb  = ((kt + 2) & 3) << 15;
    const int ktn = (kt + 2 < NT) ? kt + 2 : NT - 1;   // tail: restage last (never read)
    const int tA = ktn < 24 ? ktn : ktn - 24;          // [Xh|Xh|Xl]
    const int tB = ktn < 48 ? ktn : ktn - 48;          // [Rh|Rl|Rh]

    // retire THIS tile's 4 loads (8 -> 4 outstanding), then collective barrier
    asm volatile("s_waitcnt vmcnt(4)" ::: "memory");
    asm volatile("s_barrier" ::: "memory");

    f16x8 a[4], b[4], a2[4];
    // ---- phase 0: read a0-3 + b0-3 (interleaved), issue STAGE_A(T+2), MFMA mi0-3 ----
    a[0] = *(const f16x8*)(smem + dbuf + offA[0]);
    b[0] = *(const f16x8*)(smem + dbuf + offB[0]);
    a[1] = *(const f16x8*)(smem + dbuf + offA[1]);
    b[1] = *(const f16x8*)(smem + dbuf + offB[1]);
    a[2] = *(const f16x8*)(smem + dbuf + offA[2]);
    b[2] = *(const f16x8*)(smem + dbuf + offB[2]);
    a[3] = *(const f16x8*)(smem + dbuf + offA[3]);
    b[3] = *(const f16x8*)(smem + dbuf + offB[3]);
    STAGE_A(sdb, tA * 64);
    asm volatile("s_waitcnt lgkmcnt(0)" ::: "memory");
    __builtin_amdgcn_sched_barrier(0);
    __builtin_amdgcn_s_setprio(1);
#pragma unroll
    for (int mi = 0; mi < 4; ++mi)
#pragma unroll
      for (int ni = 0; ni < 4; ++ni)
        acc[mi][ni] = __builtin_amdgcn_mfma_f32_16x16x32_f16(a[mi], b[ni], acc[mi][ni], 0, 0, 0);
    __builtin_amdgcn_s_setprio(0);

    // ---- phase 1: read a4-7, issue STAGE_B(T+2), MFMA mi4-7 ----
    a2[0] = *(const f16x8*)(smem + dbuf + offA[4]);
    a2[1] = *(const f16x8*)(smem + dbuf + offA[5]);
    a2[2] = *(const f16x8*)(smem + dbuf + offA[6]);
    a2[3] = *(const f16x8*)(smem + dbuf + offA[7]);
    STAGE_B(sdb, tB * 64);
    asm volatile("s_waitcnt lgkmcnt(0)" ::: "memory");
    __builtin_amdgcn_sched_barrier(0);
    __builtin_amdgcn_s_setprio(1);
#pragma unroll
    for (int mi = 0; mi < 4; ++mi)
#pragma unroll
      for (int ni = 0; ni < 4; ++ni)
        acc[4 + mi][ni] = __builtin_amdgcn_mfma_f32_16x16x32_f16(a2[mi], b[ni], acc[4 + mi][ni], 0, 0, 0);
    __builtin_amdgcn_s_setprio(0);
  }

  // drain tail junk stages; then LDS is ours for the epilogue
  asm volatile("s_waitcnt vmcnt(0)" ::: "memory");
  __syncthreads();

  // ---- epilogue: wave-private transpose -> per-row top-4 over 64-col stripe ----
  float rv[4];
#pragma unroll
  for (int ni = 0; ni < 4; ++ni) rv[ni] = r2g[n0 + wn * 64 + ni * 16 + ln15];
  float* sw = (float*)smem + wid * 2112;   // [32][66] f32, wave-private
  const int rr = lane >> 1, hh = lane & 1;
#pragma unroll
  for (int P = 0; P < 4; ++P) {
#pragma unroll
    for (int mh = 0; mh < 2; ++mh)
#pragma unroll
      for (int ni = 0; ni < 4; ++ni)
#pragma unroll
        for (int r = 0; r < 4; ++r) {
          const int row_l = mh * 16 + g4 * 4 + r;   // C/D: col=lane&15, row=(lane>>4)*4+reg
          sw[row_l * 66 + ni * 16 + ln15] = rv[ni] - 2.0f * acc[2 * P + mh][ni][r];
        }
    asm volatile("s_waitcnt lgkmcnt(0)" ::: "memory");
    __builtin_amdgcn_sched_barrier(0);
    float s[4]  = {1e30f, 1e30f, 1e30f, 1e30f};
    int   id[4] = {0x7fffffff, 0x7fffffff, 0x7fffffff, 0x7fffffff};
    const float* rowp = sw + rr * 66 + hh * 32;
    const int cb = n0 + wn * 64 + hh * 32;
#pragma unroll
    for (int j = 0; j < 16; ++j) {
      const float2 v = *(const float2*)(rowp + j * 2);
      insert4(s, id, v.x, cb + j * 2);
      insert4(s, id, v.y, cb + j * 2 + 1);
    }
    float os[4]; int oid[4];
#pragma unroll
    for (int j = 0; j < 4; ++j) { os[j] = __shfl_xor(s[j], 1); oid[j] = __shfl_xor(id[j], 1); }
    merge_top4(s, id, os, oid);
    if (hh == 0) {
      const int q = m0 + wm * 128 + P * 32 + rr;
      const int base = (q * NL + bx * 4 + wn) * 4;
#pragma unroll
      for (int j = 0; j < 4; ++j) { pscore[base + j] = s[j]; pidx[base + j] = id[j]; }
    }
    asm volatile("s_waitcnt lgkmcnt(0)" ::: "memory");
  }
#undef STAGE_A
#undef STAGE_B
}

// ---------- merge NLISTS partial lists per query -> final 4 indices ----------
template <int NLISTS>
__global__ __launch_bounds__(64)
void select_kernel(const float* __restrict__ pscore, const int* __restrict__ pidx,
                   int* __restrict__ final4) {
  const int t = blockIdx.x, lane = threadIdx.x;
  constexpr int LPL = NLISTS / 64;
  float s[4]  = {1e30f, 1e30f, 1e30f, 1e30f};
  int   id[4] = {0x7fffffff, 0x7fffffff, 0x7fffffff, 0x7fffffff};
#pragma unroll
  for (int li = 0; li < LPL; ++li) {
    const int base = (t * NLISTS + lane * LPL + li) * 4;
    const float4 sv = *(const float4*)&pscore[base];
    const int4   iv = *(const int4*)&pidx[base];
    float os[4] = {sv.x, sv.y, sv.z, sv.w};
    int  oid[4] = {iv.x, iv.y, iv.z, iv.w};
    merge_top4(s, id, os, oid);
  }
#pragma unroll
  for (int mask = 1; mask < 64; mask <<= 1) {
    float os[4]; int oid[4];
#pragma unroll
    for (int j = 0; j < 4; ++j) {
      os[j]  = __shfl_xor(s[j], mask);
      oid[j] = __shfl_xor(id[j], mask);
    }
    merge_top4(s, id, os, oid);
  }
  if (lane == 0) {
    int4 o; o.x = id[0]; o.y = id[1]; o.z = id[2]; o.w = id[3];
    *(int4*)&final4[t * 4] = o;
  }
}

// ---------- gather 4 neighbors, average, write [d][T] ----------
__global__ __launch_bounds__(256)
void gather_kernel(const float* __restrict__ R, const int* __restrict__ final4,
                   float* __restrict__ out) {
  __shared__ int ids[64][4];
  const int tx = threadIdx.x & 63, ty = threadIdx.x >> 6;
  const int t0 = blockIdx.x * 64;
  ((int*)ids)[threadIdx.x] = final4[t0 * 4 + threadIdx.x];
  __syncthreads();
  const int d = blockIdx.y * 4 + ty;
  const float* row = R + (size_t)d * N_REF;
  const float sum = row[ids[tx][0]] + row[ids[tx][1]] + row[ids[tx][2]] + row[ids[tx][3]];
  out[(size_t)d * T_Q + t0 + tx] = 0.25f * sum;
}

// ---------- fallback fp32 pipeline (round-1, known correct) ----------
#define FBM 64
#define FBN 256
#define FBK 16
#define FNL (N_REF / FBN)
__global__ __launch_bounds__(256)
void score_topk_kernel(const float* __restrict__ X, const float* __restrict__ R,
                       const float* __restrict__ r2,
                       float* __restrict__ pscore, int* __restrict__ pidx) {
  __shared__ float As[FBK][FBM];
  __shared__ float Bs[FBK][FBN];
  __shared__ float r2s[FBN];
  const int tid = threadIdx.x;
  const int tx = tid & 15, ty = tid >> 4;
  const int m0 = blockIdx.y * FBM;
  const int n0 = blockIdx.x * FBN;
  r2s[tid] = r2[n0 + tid];
  float acc[4][16];
#pragma unroll
  for (int i = 0; i < 4; ++i)
#pragma unroll
    for (int j = 0; j < 16; ++j) acc[i][j] = 0.f;
  for (int k0 = 0; k0 < DIM; k0 += FBK) {
    {
      const int k = tid >> 4, m4 = tid & 15;
      const float4 av = *(const float4*)&X[(size_t)(k0 + k) * T_Q + m0 + m4 * 4];
      *(float4*)&As[k][m4 * 4] = av;
    }
#pragma unroll
    for (int i = 0; i < 4; ++i) {
      const int idx4 = tid + i * 256;
      const int k = idx4 >> 6, n4 = idx4 & 63;
      const float4 bv = *(const float4*)&R[(size_t)(k0 + k) * N_REF + n0 + n4 * 4];
      *(float4*)&Bs[k][n4 * 4] = bv;
    }
    __syncthreads();
#pragma unroll
    for (int k = 0; k < FBK; ++k) {
      float av[4], bv[16];
      *(float4*)av = *(const float4*)&As[k][ty * 4];
#pragma unroll
      for (int c = 0; c < 4; ++c)
        *(float4*)&bv[c * 4] = *(const float4*)&Bs[k][tx * 4 + c * 64];
#pragma unroll
      for (int mi = 0; mi < 4; ++mi)
#pragma unroll
        for (int ni = 0; ni < 16; ++ni) acc[mi][ni] += av[mi] * bv[ni];
    }
    __syncthreads();
  }
#pragma unroll
  for (int mi = 0; mi < 4; ++mi) {
    float s[4]  = {1e30f, 1e30f, 1e30f, 1e30f};
    int   id[4] = {0x7fffffff, 0x7fffffff, 0x7fffffff, 0x7fffffff};
#pragma unroll
    for (int c = 0; c < 4; ++c)
#pragma unroll
      for (int j = 0; j < 4; ++j) {
        const int nl = tx * 4 + c * 64 + j;
        const float sc = r2s[nl] - 2.0f * acc[mi][c * 4 + j];
        insert4(s, id, sc, n0 + nl);
      }
#pragma unroll
    for (int mask = 1; mask < 16; mask <<= 1) {
      float os[4]; int oid[4];
#pragma unroll
      for (int j = 0; j < 4; ++j) {
        os[j]  = __shfl_xor(s[j], mask);
        oid[j] = __shfl_xor(id[j], mask);
      }
      merge_top4(s, id, os, oid);
    }
    if (tx == 0) {
      const int t = m0 + ty * 4 + mi;
      const int base = (t * FNL + (int)blockIdx.x) * 4;
#pragma unroll
      for (int j = 0; j < 4; ++j) { pscore[base + j] = s[j]; pidx[base + j] = id[j]; }
    }
  }
}

extern "C" void kernel_launch(void* const* d_in, const int* in_sizes, int n_in,
                              void* d_out, int out_size, void* d_ws, size_t ws_size,
                              hipStream_t stream) {
  const float* X = (const float*)d_in[0];   // [768][2048]
  const float* R = (const float*)d_in[1];   // [768][16384]
  float* out = (float*)d_out;               // [768][2048]

  const size_t szA2 = (size_t)T_Q * KP2 * sizeof(f16);       // 6,291,456
  const size_t szB2 = (size_t)N_REF * KP2 * sizeof(f16);     // 50,331,648
  const size_t szr2 = (size_t)N_REF * sizeof(float);         // 65,536
  const size_t szPS = (size_t)T_Q * NL * 4 * sizeof(float);  // 8,388,608
  const size_t need = szA2 + szB2 + szr2 + 2 * szPS + (size_t)T_Q * 4 * sizeof(int);

  if (ws_size >= need) {
    char* w = (char*)d_ws;
    f16* A2 = (f16*)w;            w += szA2;
    f16* B2 = (f16*)w;            w += szB2;
    float* r2     = (float*)w;    w += szr2;
    float* pscore = (float*)w;    w += szPS;
    int*   pidx   = (int*)w;      w += szPS;
    int*   final4 = (int*)w;

    hipLaunchKernelGGL(r2_kernel, dim3(N_REF / 64), dim3(256), 0, stream, R, r2);
    hipLaunchKernelGGL(tsplit_kernel, dim3(T_Q / 64, DIM / 64), dim3(256), 0, stream,
                       X, A2, T_Q);
    hipLaunchKernelGGL(tsplit_kernel, dim3(N_REF / 64, DIM / 64), dim3(256), 0, stream,
                       R, B2, N_REF);
    hipLaunchKernelGGL(mfma32_topk_kernel, dim3((N_REF / BN) * (T_Q / BM)), dim3(512), 0, stream,
                       A2, B2, r2, pscore, pidx);
    hipLaunchKernelGGL((select_kernel<NL>), dim3(T_Q), dim3(64), 0, stream,
                       pscore, pidx, final4);
    hipLaunchKernelGGL(gather_kernel, dim3(T_Q / 64, DIM / 4), dim3(256), 0, stream,
                       R, final4, out);
  } else {
    // fallback: fp32 pipeline (~4.2 MB ws)
    char* w = (char*)d_ws;
    float* r2     = (float*)w;  w += szr2;
    float* pscore = (float*)w;  w += (size_t)T_Q * FNL * 4 * sizeof(float);
    int*   pidx   = (int*)w;    w += (size_t)T_Q * FNL * 4 * sizeof(int);
    int*   final4 = (int*)w;

    hipLaunchKernelGGL(r2_kernel, dim3(N_REF / 64), dim3(256), 0, stream, R, r2);
    hipLaunchKernelGGL(score_topk_kernel, dim3(N_REF / FBN, T_Q / FBM), dim3(256), 0, stream,
                       X, R, r2, pscore, pidx);
    hipLaunchKernelGGL((select_kernel<FNL>), dim3(T_Q), dim3(64), 0, stream,
                       pscore, pidx, final4);
    hipLaunchKernelGGL(gather_kernel, dim3(T_Q / 64, DIM / 4), dim3(256), 0, stream,
                       R, final4, out);
  }
}

// Round 9
// 259.922 us; speedup vs baseline: 5.2039x; 1.0071x over previous
//
#include <hip/hip_runtime.h>
#include <stdint.h>

#define T_Q   2048
#define N_REF 16384
#define DIM   768
#define KP2   1536        // packed K cols: [hi | lo]
#define NT    36          // logical K' = 2304 = 36 tiles of 64
#define BM    256
#define BN    256
#define NL    256         // partial top-4 lists per query

using f16   = _Float16;
using f16x4 = __attribute__((ext_vector_type(4))) _Float16;
using f16x8 = __attribute__((ext_vector_type(8))) _Float16;
using f32x4 = __attribute__((ext_vector_type(4))) float;

// ---------- lexicographic top-4 helpers (static indices only) ----------
__device__ __forceinline__ bool lex_less(float sa, int ia, float sb, int ib) {
  return (sa < sb) || (sa == sb && ia < ib);
}
#define CE_PAIR(s0, i0, s1, i1)                                        \
  { if (lex_less(s1, i1, s0, i0)) { float _ts = s0; s0 = s1; s1 = _ts; \
                                    int _ti = i0; i0 = i1; i1 = _ti; } }
#define PICKMIN(as, ai, bs, bi, rs, ri)                   \
  { if (lex_less(bs, bi, as, ai)) { rs = bs; ri = bi; }   \
    else                          { rs = as; ri = ai; } }

__device__ __forceinline__ void insert4(float s[4], int id[4], float sc, int n) {
  if (lex_less(sc, n, s[3], id[3])) {
    s[3] = sc; id[3] = n;
    CE_PAIR(s[2], id[2], s[3], id[3]);
    CE_PAIR(s[1], id[1], s[2], id[2]);
    CE_PAIR(s[0], id[0], s[1], id[1]);
  }
}
__device__ __forceinline__ void merge_top4(float s[4], int id[4],
                                           const float os[4], const int oid[4]) {
  float l0, l1, l2, l3; int j0, j1, j2, j3;
  PICKMIN(s[0], id[0], os[3], oid[3], l0, j0);
  PICKMIN(s[1], id[1], os[2], oid[2], l1, j1);
  PICKMIN(s[2], id[2], os[1], oid[1], l2, j2);
  PICKMIN(s[3], id[3], os[0], oid[0], l3, j3);
  CE_PAIR(l0, j0, l2, j2);
  CE_PAIR(l1, j1, l3, j3);
  CE_PAIR(l0, j0, l1, j1);
  CE_PAIR(l2, j2, l3, j3);
  s[0] = l0; s[1] = l1; s[2] = l2; s[3] = l3;
  id[0] = j0; id[1] = j1; id[2] = j2; id[3] = j3;
}

__device__ __forceinline__ void gl_lds16(const void* g, void* l) {
  __builtin_amdgcn_global_load_lds((const __attribute__((address_space(1))) uint32_t*)g,
                                   (__attribute__((address_space(3))) uint32_t*)l, 16, 0, 0);
}

// ---------- r2[n] = ||ref_n||^2 (fp32 exact) ----------
__global__ __launch_bounds__(256)
void r2_kernel(const float* __restrict__ R, float* __restrict__ r2) {
  __shared__ float red[256];
  const int lane = threadIdx.x & 63;
  const int dg   = threadIdx.x >> 6;
  const int n    = blockIdx.x * 64 + lane;
  float acc = 0.f;
  const int d0 = dg * (DIM / 4), d1 = d0 + (DIM / 4);
  for (int d = d0; d < d1; ++d) {
    float v = R[(size_t)d * N_REF + n];
    acc += v * v;
  }
  red[threadIdx.x] = acc;
  __syncthreads();
  if (threadIdx.x < 64)
    r2[n] = red[lane] + red[lane + 64] + red[lane + 128] + red[lane + 192];
}

// ---------- transpose + f16 hi/lo split: in[D][W] -> out[W][1536] = [hi | lo] ----------
__global__ __launch_bounds__(256)
void tsplit_kernel(const float* __restrict__ in, f16* __restrict__ out, int W) {
  __shared__ f16 lh[64][66], ll[64][66];
  const int c0 = blockIdx.x * 64, d0 = blockIdx.y * 64;
  const int q = threadIdx.x & 15, p = threadIdx.x >> 4;
#pragma unroll
  for (int i = 0; i < 4; ++i) {
    const int dl = p + i * 16;
    const float4 v = *(const float4*)&in[(size_t)(d0 + dl) * W + c0 + q * 4];
    const f16 h0 = (f16)v.x, h1 = (f16)v.y, h2 = (f16)v.z, h3 = (f16)v.w;
    lh[q * 4 + 0][dl] = h0; ll[q * 4 + 0][dl] = (f16)(v.x - (float)h0);
    lh[q * 4 + 1][dl] = h1; ll[q * 4 + 1][dl] = (f16)(v.y - (float)h1);
    lh[q * 4 + 2][dl] = h2; ll[q * 4 + 2][dl] = (f16)(v.z - (float)h2);
    lh[q * 4 + 3][dl] = h3; ll[q * 4 + 3][dl] = (f16)(v.w - (float)h3);
  }
  __syncthreads();
  const int rl = threadIdx.x >> 2, seg = threadIdx.x & 3;
  f16* rowo = out + (size_t)(c0 + rl) * KP2 + d0;
#pragma unroll
  for (int j = 0; j < 4; ++j) {
    const int dd = seg * 16 + j * 4;
    f16x4 vh = *(const f16x4*)&lh[rl][dd];
    f16x4 vl = *(const f16x4*)&ll[rl][dd];
    *(f16x4*)&rowo[dd] = vh;
    *(f16x4*)&rowo[768 + dd] = vl;
  }
}

// ---------- m201-template 4-phase/K-tile MFMA GEMM (BK=64) + fused top-4 ----------
// Logical K' = 2304 over NT=36 tiles of 64: A limbs [Xh|Xh|Xl], B limbs [Rh|Rl|Rh].
// Per tile T: 4 fine phases, each {ds-reads ; stage 1 half ; [vmcnt] ; s_barrier ;
// lgkmcnt(0)+sched_barrier ; setprio1 ; 16 MFMA ; setprio0 ; s_barrier}.
// Stage order per tile: B-ks0, B-ks1, A-ks0, A-ks1 (for T+1).
// vmcnt(4) end of P1 retires prior tile's A-ks1 (read in P2/P3);
// vmcnt(2) end of P3 retires T+1's B0,B1,A0 (read next P0). Never 0 in-loop.
__global__ __launch_bounds__(512, 2)
void mfma4p_topk_kernel(const f16* __restrict__ A2, const f16* __restrict__ B2,
                        const float* __restrict__ r2g,
                        float* __restrict__ pscore, int* __restrict__ pidx) {
  // LDS: 2 dbufs of 64 KB at d*65536: A-ks0 @0, A-ks1 @16384, B-ks0 @32768, B-ks1 @49152.
  // Region: 256 rows x 32 K-cols f16 (64 B rows); 16B slot swizzle: slot ^= (row>>1)&3.
  __shared__ __align__(16) char smem[131072];
  const int tid  = threadIdx.x;
  const int lane = tid & 63, wid = tid >> 6;
  const int wm = wid >> 2, wn = wid & 3;
  const int ln15 = lane & 15, g4 = lane >> 4;

  // supertile XCD mapping: XCD (flat&7) owns bx in [8x, 8x+8), all by
  const int flat = (int)blockIdx.x;
  const int jj = flat >> 3;
  const int bx = (flat & 7) * 8 + (jj & 7);  // 0..63
  const int by = jj >> 3;                    // 0..7
  const int m0 = by * BM, n0 = bx * BN;

  // ---- staging: 2 gl_lds(16B) per thread per 16 KB half-region ----
  // LDS slot s: row = s>>2, lslot = s&3 ; global slot = lslot ^ ((s>>3)&3)
  const int s0 = tid, s1 = tid + 512;
  const int r0 = s0 >> 2, r1 = s1 >> 2;
  const int c0b = (((s0 & 3) ^ ((s0 >> 3) & 3)) << 4);
  const int c1b = (((s1 & 3) ^ ((s1 >> 3) & 3)) << 4);
  const char* gA0 = (const char*)(A2 + (size_t)(m0 + r0) * KP2) + c0b;
  const char* gA1 = (const char*)(A2 + (size_t)(m0 + r1) * KP2) + c1b;
  const char* gB0 = (const char*)(B2 + (size_t)(n0 + r0) * KP2) + c0b;
  const char* gB1 = (const char*)(B2 + (size_t)(n0 + r1) * KP2) + c1b;
  const int l0 = s0 * 16, l1 = s1 * 16;

#define STAGE_A(bufo, rego, kbyte)                                   \
  { gl_lds16(gA0 + (kbyte), smem + (bufo) + (rego) + l0);            \
    gl_lds16(gA1 + (kbyte), smem + (bufo) + (rego) + l1); }
#define STAGE_B(bufo, rego, kbyte)                                   \
  { gl_lds16(gB0 + (kbyte), smem + (bufo) + (rego) + l0);            \
    gl_lds16(gB1 + (kbyte), smem + (bufo) + (rego) + l1); }

  // ---- fragment LDS offsets (region-relative): lane reads global slot g4 of its row ----
  const int cswz = ((g4 ^ ((ln15 >> 1) & 3)) << 4);
  int offA[8], offB[4];
#pragma unroll
  for (int mi = 0; mi < 8; ++mi) offA[mi] = (wm * 128 + mi * 16 + ln15) * 64 + cswz;
#pragma unroll
  for (int ni = 0; ni < 4; ++ni) offB[ni] = 32768 + (wn * 64 + ni * 16 + ln15) * 64 + cswz;

  f32x4 acc[8][4] = {};

  // prologue: stage tile 0 into dbuf0, order B-ks0, B-ks1, A-ks0, A-ks1 (8 loads);
  // vmcnt(2) retires B0,B1,A0 (leaves A-ks1's 2) -> collective barrier.
  STAGE_B(0, 32768, 0);
  STAGE_B(0, 49152, 64);
  STAGE_A(0, 0, 0);
  STAGE_A(0, 16384, 64);
  asm volatile("s_waitcnt vmcnt(2)" ::: "memory");
  __syncthreads();

  for (int kt = 0; kt < NT; ++kt) {
    const int dbuf = (kt & 1) << 16;
    const int sdb  = ((kt + 1) & 1) << 16;
    const int ktn = (kt + 1 < NT) ? kt + 1 : NT - 1;   // tail: restage last (never read)
    const int tA = ktn < 12 ? ktn : ktn - 12;          // [Xh|Xh|Xl]
    const int tB = ktn < 24 ? ktn : ktn - 24;          // [Rh|Rl|Rh]
    const int kbA = tA * 128, kbB = tB * 128;
    f16x8 a[4], a2[4], b[4];

    // ===== P0: reads a0-3+b0-3 (ks0); stage B-ks0(T+1) =====
    a[0] = *(const f16x8*)(smem + dbuf + offA[0]);
    b[0] = *(const f16x8*)(smem + dbuf + offB[0]);
    a[1] = *(const f16x8*)(smem + dbuf + offA[1]);
    b[1] = *(const f16x8*)(smem + dbuf + offB[1]);
    a[2] = *(const f16x8*)(smem + dbuf + offA[2]);
    b[2] = *(const f16x8*)(smem + dbuf + offB[2]);
    a[3] = *(const f16x8*)(smem + dbuf + offA[3]);
    b[3] = *(const f16x8*)(smem + dbuf + offB[3]);
    STAGE_B(sdb, 32768, kbB);
    asm volatile("s_barrier" ::: "memory");
    asm volatile("s_waitcnt lgkmcnt(0)" ::: "memory");
    __builtin_amdgcn_sched_barrier(0);
    __builtin_amdgcn_s_setprio(1);
#pragma unroll
    for (int mi = 0; mi < 4; ++mi)
#pragma unroll
      for (int ni = 0; ni < 4; ++ni)
        acc[mi][ni] = __builtin_amdgcn_mfma_f32_16x16x32_f16(a[mi], b[ni], acc[mi][ni], 0, 0, 0);
    __builtin_amdgcn_s_setprio(0);
    asm volatile("s_barrier" ::: "memory");

    // ===== P1: reads a4-7 (ks0); stage B-ks1(T+1); vmcnt(4) =====
    a2[0] = *(const f16x8*)(smem + dbuf + offA[4]);
    a2[1] = *(const f16x8*)(smem + dbuf + offA[5]);
    a2[2] = *(const f16x8*)(smem + dbuf + offA[6]);
    a2[3] = *(const f16x8*)(smem + dbuf + offA[7]);
    STAGE_B(sdb, 49152, kbB + 64);
    asm volatile("s_waitcnt vmcnt(4)" ::: "memory");   // retire prior tile's A-ks1
    asm volatile("s_barrier" ::: "memory");
    asm volatile("s_waitcnt lgkmcnt(0)" ::: "memory");
    __builtin_amdgcn_sched_barrier(0);
    __builtin_amdgcn_s_setprio(1);
#pragma unroll
    for (int mi = 0; mi < 4; ++mi)
#pragma unroll
      for (int ni = 0; ni < 4; ++ni)
        acc[4 + mi][ni] = __builtin_amdgcn_mfma_f32_16x16x32_f16(a2[mi], b[ni], acc[4 + mi][ni], 0, 0, 0);
    __builtin_amdgcn_s_setprio(0);
    asm volatile("s_barrier" ::: "memory");

    // ===== P2: reads a0-3+b0-3 (ks1); stage A-ks0(T+1) =====
    a[0] = *(const f16x8*)(smem + dbuf + 16384 + offA[0]);
    b[0] = *(const f16x8*)(smem + dbuf + 16384 + offB[0]);
    a[1] = *(const f16x8*)(smem + dbuf + 16384 + offA[1]);
    b[1] = *(const f16x8*)(smem + dbuf + 16384 + offB[1]);
    a[2] = *(const f16x8*)(smem + dbuf + 16384 + offA[2]);
    b[2] = *(const f16x8*)(smem + dbuf + 16384 + offB[2]);
    a[3] = *(const f16x8*)(smem + dbuf + 16384 + offA[3]);
    b[3] = *(const f16x8*)(smem + dbuf + 16384 + offB[3]);
    STAGE_A(sdb, 0, kbA);
    asm volatile("s_barrier" ::: "memory");
    asm volatile("s_waitcnt lgkmcnt(0)" ::: "memory");
    __builtin_amdgcn_sched_barrier(0);
    __builtin_amdgcn_s_setprio(1);
#pragma unroll
    for (int mi = 0; mi < 4; ++mi)
#pragma unroll
      for (int ni = 0; ni < 4; ++ni)
        acc[mi][ni] = __builtin_amdgcn_mfma_f32_16x16x32_f16(a[mi], b[ni], acc[mi][ni], 0, 0, 0);
    __builtin_amdgcn_s_setprio(0);
    asm volatile("s_barrier" ::: "memory");

    // ===== P3: reads a4-7 (ks1); stage A-ks1(T+1); vmcnt(2) =====
    a2[0] = *(const f16x8*)(smem + dbuf + 16384 + offA[4]);
    a2[1] = *(const f16x8*)(smem + dbuf + 16384 + offA[5]);
    a2[2] = *(const f16x8*)(smem + dbuf + 16384 + offA[6]);
    a2[3] = *(const f16x8*)(smem + dbuf + 16384 + offA[7]);
    STAGE_A(sdb, 16384, kbA + 64);
    asm volatile("s_waitcnt vmcnt(2)" ::: "memory");   // retire T+1's B0,B1,A0
    asm volatile("s_barrier" ::: "memory");
    asm volatile("s_waitcnt lgkmcnt(0)" ::: "memory");
    __builtin_amdgcn_sched_barrier(0);
    __builtin_amdgcn_s_setprio(1);
#pragma unroll
    for (int mi = 0; mi < 4; ++mi)
#pragma unroll
      for (int ni = 0; ni < 4; ++ni)
        acc[4 + mi][ni] = __builtin_amdgcn_mfma_f32_16x16x32_f16(a2[mi], b[ni], acc[4 + mi][ni], 0, 0, 0);
    __builtin_amdgcn_s_setprio(0);
    asm volatile("s_barrier" ::: "memory");
  }

  // drain tail junk stages; then LDS is ours for the epilogue
  asm volatile("s_waitcnt vmcnt(0)" ::: "memory");
  __syncthreads();

  // ---- epilogue: wave-private transpose -> per-row top-4 over 64-col stripe ----
  float rv[4];
#pragma unroll
  for (int ni = 0; ni < 4; ++ni) rv[ni] = r2g[n0 + wn * 64 + ni * 16 + ln15];
  float* sw = (float*)smem + wid * 2112;   // [32][66] f32, wave-private
  const int rr = lane >> 1, hh = lane & 1;
#pragma unroll
  for (int P = 0; P < 4; ++P) {
#pragma unroll
    for (int mh = 0; mh < 2; ++mh)
#pragma unroll
      for (int ni = 0; ni < 4; ++ni)
#pragma unroll
        for (int r = 0; r < 4; ++r) {
          const int row_l = mh * 16 + g4 * 4 + r;   // C/D: col=lane&15, row=(lane>>4)*4+reg
          sw[row_l * 66 + ni * 16 + ln15] = rv[ni] - 2.0f * acc[2 * P + mh][ni][r];
        }
    asm volatile("s_waitcnt lgkmcnt(0)" ::: "memory");
    __builtin_amdgcn_sched_barrier(0);
    float s[4]  = {1e30f, 1e30f, 1e30f, 1e30f};
    int   id[4] = {0x7fffffff, 0x7fffffff, 0x7fffffff, 0x7fffffff};
    const float* rowp = sw + rr * 66 + hh * 32;
    const int cb = n0 + wn * 64 + hh * 32;
#pragma unroll
    for (int j = 0; j < 16; ++j) {
      const float2 v = *(const float2*)(rowp + j * 2);
      insert4(s, id, v.x, cb + j * 2);
      insert4(s, id, v.y, cb + j * 2 + 1);
    }
    float os[4]; int oid[4];
#pragma unroll
    for (int j = 0; j < 4; ++j) { os[j] = __shfl_xor(s[j], 1); oid[j] = __shfl_xor(id[j], 1); }
    merge_top4(s, id, os, oid);
    if (hh == 0) {
      const int q = m0 + wm * 128 + P * 32 + rr;
      const int base = (q * NL + bx * 4 + wn) * 4;
#pragma unroll
      for (int j = 0; j < 4; ++j) { pscore[base + j] = s[j]; pidx[base + j] = id[j]; }
    }
    asm volatile("s_waitcnt lgkmcnt(0)" ::: "memory");
  }
#undef STAGE_A
#undef STAGE_B
}

// ---------- merge NLISTS partial lists per query -> final 4 indices ----------
template <int NLISTS>
__global__ __launch_bounds__(64)
void select_kernel(const float* __restrict__ pscore, const int* __restrict__ pidx,
                   int* __restrict__ final4) {
  const int t = blockIdx.x, lane = threadIdx.x;
  constexpr int LPL = NLISTS / 64;
  float s[4]  = {1e30f, 1e30f, 1e30f, 1e30f};
  int   id[4] = {0x7fffffff, 0x7fffffff, 0x7fffffff, 0x7fffffff};
#pragma unroll
  for (int li = 0; li < LPL; ++li) {
    const int base = (t * NLISTS + lane * LPL + li) * 4;
    const float4 sv = *(const float4*)&pscore[base];
    const int4   iv = *(const int4*)&pidx[base];
    float os[4] = {sv.x, sv.y, sv.z, sv.w};
    int  oid[4] = {iv.x, iv.y, iv.z, iv.w};
    merge_top4(s, id, os, oid);
  }
#pragma unroll
  for (int mask = 1; mask < 64; mask <<= 1) {
    float os[4]; int oid[4];
#pragma unroll
    for (int j = 0; j < 4; ++j) {
      os[j]  = __shfl_xor(s[j], mask);
      oid[j] = __shfl_xor(id[j], mask);
    }
    merge_top4(s, id, os, oid);
  }
  if (lane == 0) {
    int4 o; o.x = id[0]; o.y = id[1]; o.z = id[2]; o.w = id[3];
    *(int4*)&final4[t * 4] = o;
  }
}

// ---------- gather 4 neighbors, average, write [d][T] ----------
__global__ __launch_bounds__(256)
void gather_kernel(const float* __restrict__ R, const int* __restrict__ final4,
                   float* __restrict__ out) {
  __shared__ int ids[64][4];
  const int tx = threadIdx.x & 63, ty = threadIdx.x >> 6;
  const int t0 = blockIdx.x * 64;
  ((int*)ids)[threadIdx.x] = final4[t0 * 4 + threadIdx.x];
  __syncthreads();
  const int d = blockIdx.y * 4 + ty;
  const float* row = R + (size_t)d * N_REF;
  const float sum = row[ids[tx][0]] + row[ids[tx][1]] + row[ids[tx][2]] + row[ids[tx][3]];
  out[(size_t)d * T_Q + t0 + tx] = 0.25f * sum;
}

// ---------- fallback fp32 pipeline (round-1, known correct) ----------
#define FBM 64
#define FBN 256
#define FBK 16
#define FNL (N_REF / FBN)
__global__ __launch_bounds__(256)
void score_topk_kernel(const float* __restrict__ X, const float* __restrict__ R,
                       const float* __restrict__ r2,
                       float* __restrict__ pscore, int* __restrict__ pidx) {
  __shared__ float As[FBK][FBM];
  __shared__ float Bs[FBK][FBN];
  __shared__ float r2s[FBN];
  const int tid = threadIdx.x;
  const int tx = tid & 15, ty = tid >> 4;
  const int m0 = blockIdx.y * FBM;
  const int n0 = blockIdx.x * FBN;
  r2s[tid] = r2[n0 + tid];
  float acc[4][16];
#pragma unroll
  for (int i = 0; i < 4; ++i)
#pragma unroll
    for (int j = 0; j < 16; ++j) acc[i][j] = 0.f;
  for (int k0 = 0; k0 < DIM; k0 += FBK) {
    {
      const int k = tid >> 4, m4 = tid & 15;
      const float4 av = *(const float4*)&X[(size_t)(k0 + k) * T_Q + m0 + m4 * 4];
      *(float4*)&As[k][m4 * 4] = av;
    }
#pragma unroll
    for (int i = 0; i < 4; ++i) {
      const int idx4 = tid + i * 256;
      const int k = idx4 >> 6, n4 = idx4 & 63;
      const float4 bv = *(const float4*)&R[(size_t)(k0 + k) * N_REF + n0 + n4 * 4];
      *(float4*)&Bs[k][n4 * 4] = bv;
    }
    __syncthreads();
#pragma unroll
    for (int k = 0; k < FBK; ++k) {
      float av[4], bv[16];
      *(float4*)av = *(const float4*)&As[k][ty * 4];
#pragma unroll
      for (int c = 0; c < 4; ++c)
        *(float4*)&bv[c * 4] = *(const float4*)&Bs[k][tx * 4 + c * 64];
#pragma unroll
      for (int mi = 0; mi < 4; ++mi)
#pragma unroll
        for (int ni = 0; ni < 16; ++ni) acc[mi][ni] += av[mi] * bv[ni];
    }
    __syncthreads();
  }
#pragma unroll
  for (int mi = 0; mi < 4; ++mi) {
    float s[4]  = {1e30f, 1e30f, 1e30f, 1e30f};
    int   id[4] = {0x7fffffff, 0x7fffffff, 0x7fffffff, 0x7fffffff};
#pragma unroll
    for (int c = 0; c < 4; ++c)
#pragma unroll
      for (int j = 0; j < 4; ++j) {
        const int nl = tx * 4 + c * 64 + j;
        const float sc = r2s[nl] - 2.0f * acc[mi][c * 4 + j];
        insert4(s, id, sc, n0 + nl);
      }
#pragma unroll
    for (int mask = 1; mask < 16; mask <<= 1) {
      float os[4]; int oid[4];
#pragma unroll
      for (int j = 0; j < 4; ++j) {
        os[j]  = __shfl_xor(s[j], mask);
        oid[j] = __shfl_xor(id[j], mask);
      }
      merge_top4(s, id, os, oid);
    }
    if (tx == 0) {
      const int t = m0 + ty * 4 + mi;
      const int base = (t * FNL + (int)blockIdx.x) * 4;
#pragma unroll
      for (int j = 0; j < 4; ++j) { pscore[base + j] = s[j]; pidx[base + j] = id[j]; }
    }
  }
}

extern "C" void kernel_launch(void* const* d_in, const int* in_sizes, int n_in,
                              void* d_out, int out_size, void* d_ws, size_t ws_size,
                              hipStream_t stream) {
  const float* X = (const float*)d_in[0];   // [768][2048]
  const float* R = (const float*)d_in[1];   // [768][16384]
  float* out = (float*)d_out;               // [768][2048]

  const size_t szA2 = (size_t)T_Q * KP2 * sizeof(f16);       // 6,291,456
  const size_t szB2 = (size_t)N_REF * KP2 * sizeof(f16);     // 50,331,648
  const size_t szr2 = (size_t)N_REF * sizeof(float);         // 65,536
  const size_t szPS = (size_t)T_Q * NL * 4 * sizeof(float);  // 8,388,608
  const size_t need = szA2 + szB2 + szr2 + 2 * szPS + (size_t)T_Q * 4 * sizeof(int);

  if (ws_size >= need) {
    char* w = (char*)d_ws;
    f16* A2 = (f16*)w;            w += szA2;
    f16* B2 = (f16*)w;            w += szB2;
    float* r2     = (float*)w;    w += szr2;
    float* pscore = (float*)w;    w += szPS;
    int*   pidx   = (int*)w;      w += szPS;
    int*   final4 = (int*)w;

    hipLaunchKernelGGL(r2_kernel, dim3(N_REF / 64), dim3(256), 0, stream, R, r2);
    hipLaunchKernelGGL(tsplit_kernel, dim3(T_Q / 64, DIM / 64), dim3(256), 0, stream,
                       X, A2, T_Q);
    hipLaunchKernelGGL(tsplit_kernel, dim3(N_REF / 64, DIM / 64), dim3(256), 0, stream,
                       R, B2, N_REF);
    hipLaunchKernelGGL(mfma4p_topk_kernel, dim3((N_REF / BN) * (T_Q / BM)), dim3(512), 0, stream,
                       A2, B2, r2, pscore, pidx);
    hipLaunchKernelGGL((select_kernel<NL>), dim3(T_Q), dim3(64), 0, stream,
                       pscore, pidx, final4);
    hipLaunchKernelGGL(gather_kernel, dim3(T_Q / 64, DIM / 4), dim3(256), 0, stream,
                       R, final4, out);
  } else {
    // fallback: fp32 pipeline (~4.2 MB ws)
    char* w = (char*)d_ws;
    float* r2     = (float*)w;  w += szr2;
    float* pscore = (float*)w;  w += (size_t)T_Q * FNL * 4 * sizeof(float);
    int*   pidx   = (int*)w;    w += (size_t)T_Q * FNL * 4 * sizeof(int);
    int*   final4 = (int*)w;

    hipLaunchKernelGGL(r2_kernel, dim3(N_REF / 64), dim3(256), 0, stream, R, r2);
    hipLaunchKernelGGL(score_topk_kernel, dim3(N_REF / FBN, T_Q / FBM), dim3(256), 0, stream,
                       X, R, r2, pscore, pidx);
    hipLaunchKernelGGL((select_kernel<FNL>), dim3(T_Q), dim3(64), 0, stream,
                       pscore, pidx, final4);
    hipLaunchKernelGGL(gather_kernel, dim3(T_Q / 64, DIM / 4), dim3(256), 0, stream,
                       R, final4, out);
  }
}

// Round 10
// 188.443 us; speedup vs baseline: 7.1778x; 1.3793x over previous
//
#include <hip/hip_runtime.h>
#include <stdint.h>

#define T_Q   2048
#define N_REF 16384
#define DIM   768
#define KP2   1536        // packed K cols: [hi | lo]
#define NT    24          // K = 768 = 24 tiles of 32 (hi limb only)
#define BM    256
#define BN    256
#define NL    256         // partial top-4 lists per query

using f16   = _Float16;
using f16x4 = __attribute__((ext_vector_type(4))) _Float16;
using f16x8 = __attribute__((ext_vector_type(8))) _Float16;
using f32x4 = __attribute__((ext_vector_type(4))) float;

// ---------- lexicographic top-k helpers (static indices only) ----------
__device__ __forceinline__ bool lex_less(float sa, int ia, float sb, int ib) {
  return (sa < sb) || (sa == sb && ia < ib);
}
#define CE_PAIR(s0, i0, s1, i1)                                        \
  { if (lex_less(s1, i1, s0, i0)) { float _ts = s0; s0 = s1; s1 = _ts; \
                                    int _ti = i0; i0 = i1; i1 = _ti; } }
#define PICKMIN(as, ai, bs, bi, rs, ri)                   \
  { if (lex_less(bs, bi, as, ai)) { rs = bs; ri = bi; }   \
    else                          { rs = as; ri = ai; } }

__device__ __forceinline__ void insert4(float s[4], int id[4], float sc, int n) {
  if (lex_less(sc, n, s[3], id[3])) {
    s[3] = sc; id[3] = n;
    CE_PAIR(s[2], id[2], s[3], id[3]);
    CE_PAIR(s[1], id[1], s[2], id[2]);
    CE_PAIR(s[0], id[0], s[1], id[1]);
  }
}
__device__ __forceinline__ void merge_top4(float s[4], int id[4],
                                           const float os[4], const int oid[4]) {
  float l0, l1, l2, l3; int j0, j1, j2, j3;
  PICKMIN(s[0], id[0], os[3], oid[3], l0, j0);
  PICKMIN(s[1], id[1], os[2], oid[2], l1, j1);
  PICKMIN(s[2], id[2], os[1], oid[1], l2, j2);
  PICKMIN(s[3], id[3], os[0], oid[0], l3, j3);
  CE_PAIR(l0, j0, l2, j2);
  CE_PAIR(l1, j1, l3, j3);
  CE_PAIR(l0, j0, l1, j1);
  CE_PAIR(l2, j2, l3, j3);
  s[0] = l0; s[1] = l1; s[2] = l2; s[3] = l3;
  id[0] = j0; id[1] = j1; id[2] = j2; id[3] = j3;
}

// merge two sorted(asc) 8-lists, keep smallest 8 (Batcher bitonic lower half)
__device__ __forceinline__ void merge_top8(float s[8], int id[8],
                                           const float os[8], const int oid[8]) {
  float l0,l1,l2,l3,l4,l5,l6,l7; int j0,j1,j2,j3,j4,j5,j6,j7;
  PICKMIN(s[0], id[0], os[7], oid[7], l0, j0);
  PICKMIN(s[1], id[1], os[6], oid[6], l1, j1);
  PICKMIN(s[2], id[2], os[5], oid[5], l2, j2);
  PICKMIN(s[3], id[3], os[4], oid[4], l3, j3);
  PICKMIN(s[4], id[4], os[3], oid[3], l4, j4);
  PICKMIN(s[5], id[5], os[2], oid[2], l5, j5);
  PICKMIN(s[6], id[6], os[1], oid[1], l6, j6);
  PICKMIN(s[7], id[7], os[0], oid[0], l7, j7);
  CE_PAIR(l0, j0, l4, j4); CE_PAIR(l1, j1, l5, j5);
  CE_PAIR(l2, j2, l6, j6); CE_PAIR(l3, j3, l7, j7);
  CE_PAIR(l0, j0, l2, j2); CE_PAIR(l1, j1, l3, j3);
  CE_PAIR(l4, j4, l6, j6); CE_PAIR(l5, j5, l7, j7);
  CE_PAIR(l0, j0, l1, j1); CE_PAIR(l2, j2, l3, j3);
  CE_PAIR(l4, j4, l5, j5); CE_PAIR(l6, j6, l7, j7);
  s[0]=l0; s[1]=l1; s[2]=l2; s[3]=l3; s[4]=l4; s[5]=l5; s[6]=l6; s[7]=l7;
  id[0]=j0; id[1]=j1; id[2]=j2; id[3]=j3; id[4]=j4; id[5]=j5; id[6]=j6; id[7]=j7;
}

__device__ __forceinline__ void gl_lds16(const void* g, void* l) {
  __builtin_amdgcn_global_load_lds((const __attribute__((address_space(1))) uint32_t*)g,
                                   (__attribute__((address_space(3))) uint32_t*)l, 16, 0, 0);
}

// ---------- r2[n] = ||ref_n||^2 (fp32 exact) ----------
__global__ __launch_bounds__(256)
void r2_kernel(const float* __restrict__ R, float* __restrict__ r2) {
  __shared__ float red[256];
  const int lane = threadIdx.x & 63;
  const int dg   = threadIdx.x >> 6;
  const int n    = blockIdx.x * 64 + lane;
  float acc = 0.f;
  const int d0 = dg * (DIM / 4), d1 = d0 + (DIM / 4);
  for (int d = d0; d < d1; ++d) {
    float v = R[(size_t)d * N_REF + n];
    acc += v * v;
  }
  red[threadIdx.x] = acc;
  __syncthreads();
  if (threadIdx.x < 64)
    r2[n] = red[lane] + red[lane + 64] + red[lane + 128] + red[lane + 192];
}

// ---------- transpose + f16 hi/lo split: in[D][W] -> out[W][1536] = [hi | lo] ----------
__global__ __launch_bounds__(256)
void tsplit_kernel(const float* __restrict__ in, f16* __restrict__ out, int W) {
  __shared__ f16 lh[64][66], ll[64][66];
  const int c0 = blockIdx.x * 64, d0 = blockIdx.y * 64;
  const int q = threadIdx.x & 15, p = threadIdx.x >> 4;
#pragma unroll
  for (int i = 0; i < 4; ++i) {
    const int dl = p + i * 16;
    const float4 v = *(const float4*)&in[(size_t)(d0 + dl) * W + c0 + q * 4];
    const f16 h0 = (f16)v.x, h1 = (f16)v.y, h2 = (f16)v.z, h3 = (f16)v.w;
    lh[q * 4 + 0][dl] = h0; ll[q * 4 + 0][dl] = (f16)(v.x - (float)h0);
    lh[q * 4 + 1][dl] = h1; ll[q * 4 + 1][dl] = (f16)(v.y - (float)h1);
    lh[q * 4 + 2][dl] = h2; ll[q * 4 + 2][dl] = (f16)(v.z - (float)h2);
    lh[q * 4 + 3][dl] = h3; ll[q * 4 + 3][dl] = (f16)(v.w - (float)h3);
  }
  __syncthreads();
  const int rl = threadIdx.x >> 2, seg = threadIdx.x & 3;
  f16* rowo = out + (size_t)(c0 + rl) * KP2 + d0;
#pragma unroll
  for (int j = 0; j < 4; ++j) {
    const int dd = seg * 16 + j * 4;
    f16x4 vh = *(const f16x4*)&lh[rl][dd];
    f16x4 vl = *(const f16x4*)&ll[rl][dd];
    *(f16x4*)&rowo[dd] = vh;
    *(f16x4*)&rowo[768 + dd] = vl;
  }
}

// ---------- single-product f16-hi MFMA GEMM (K=768) + fused approx top-4 ----------
// r7's proven 4-buffer depth-2 pipeline and ledger; only NT and the tile map
// changed (tA = tB = tile, hi-limb region bytes [0,1536) of each KP2 row).
// Approx scores (err ~0.014 abs); exactness restored by rescore_kernel on 8 cands.
__global__ __launch_bounds__(512, 2)
void mfma_hi_topk_kernel(const f16* __restrict__ A2, const f16* __restrict__ B2,
                         const float* __restrict__ r2g,
                         float* __restrict__ pscore, int* __restrict__ pidx) {
  // LDS: 4 rotating bufs, buf q at q*32768: A @0 (16 KB), B @16384 (16 KB).
  // Region: 256 rows x 32 K-cols f16 (64 B rows); 16B slot swizzle: slot ^= (row>>1)&3.
  __shared__ __align__(16) char smem[131072];
  const int tid  = threadIdx.x;
  const int lane = tid & 63, wid = tid >> 6;
  const int wm = wid >> 2, wn = wid & 3;
  const int ln15 = lane & 15, g4 = lane >> 4;

  // supertile XCD mapping: XCD (flat&7) owns bx in [8x, 8x+8), all by
  const int flat = (int)blockIdx.x;
  const int jj = flat >> 3;
  const int bx = (flat & 7) * 8 + (jj & 7);  // 0..63
  const int by = jj >> 3;                    // 0..7
  const int m0 = by * BM, n0 = bx * BN;

  // staging: LDS slot s: row = s>>2, lslot = s&3 ; global slot = lslot ^ ((s>>3)&3)
  const int s0 = tid, s1 = tid + 512;
  const int r0 = s0 >> 2, r1 = s1 >> 2;
  const int c0b = (((s0 & 3) ^ ((s0 >> 3) & 3)) << 4);
  const int c1b = (((s1 & 3) ^ ((s1 >> 3) & 3)) << 4);
  const char* gA0 = (const char*)(A2 + (size_t)(m0 + r0) * KP2) + c0b;
  const char* gA1 = (const char*)(A2 + (size_t)(m0 + r1) * KP2) + c1b;
  const char* gB0 = (const char*)(B2 + (size_t)(n0 + r0) * KP2) + c0b;
  const char* gB1 = (const char*)(B2 + (size_t)(n0 + r1) * KP2) + c1b;
  const int l0 = s0 * 16, l1 = s1 * 16;

#define STAGE_A(sdb, kbyte)                                      \
  { gl_lds16(gA0 + (kbyte), smem + (sdb) + l0);                  \
    gl_lds16(gA1 + (kbyte), smem + (sdb) + l1); }
#define STAGE_B(sdb, kbyte)                                      \
  { gl_lds16(gB0 + (kbyte), smem + (sdb) + 16384 + l0);          \
    gl_lds16(gB1 + (kbyte), smem + (sdb) + 16384 + l1); }

  // fragment LDS offsets (K-invariant): lane reads global slot g4 of its row
  const int cswz = ((g4 ^ ((ln15 >> 1) & 3)) << 4);
  int offA[8], offB[4];
#pragma unroll
  for (int mi = 0; mi < 8; ++mi) offA[mi] = (wm * 128 + mi * 16 + ln15) * 64 + cswz;
#pragma unroll
  for (int ni = 0; ni < 4; ++ni) offB[ni] = 16384 + (wn * 64 + ni * 16 + ln15) * 64 + cswz;

  f32x4 acc[8][4] = {};

  // prologue: stage tile 0 -> buf0, tile 1 -> buf1 (8 loads outstanding)
  STAGE_A(0, 0);
  STAGE_B(0, 0);
  STAGE_A(32768, 64);
  STAGE_B(32768, 64);

  for (int kt = 0; kt < NT; ++kt) {
    const int dbuf = (kt & 3) << 15;
    const int sdb  = ((kt + 2) & 3) << 15;
    const int ktn = (kt + 2 < NT) ? kt + 2 : NT - 1;   // tail: restage last (never read)

    // issue next+2 tile loads (that buffer drained before the last crossed barrier)
    STAGE_A(sdb, ktn * 64);
    STAGE_B(sdb, ktn * 64);
    // retire THIS tile's 4 loads (12 -> 8 outstanding), then collective barrier
    asm volatile("s_waitcnt vmcnt(8)" ::: "memory");
    asm volatile("s_barrier" ::: "memory");

    f16x8 a[8], b[4];
    a[0] = *(const f16x8*)(smem + dbuf + offA[0]);
    b[0] = *(const f16x8*)(smem + dbuf + offB[0]);
    a[1] = *(const f16x8*)(smem + dbuf + offA[1]);
    b[1] = *(const f16x8*)(smem + dbuf + offB[1]);
    a[2] = *(const f16x8*)(smem + dbuf + offA[2]);
    b[2] = *(const f16x8*)(smem + dbuf + offB[2]);
    a[3] = *(const f16x8*)(smem + dbuf + offA[3]);
    b[3] = *(const f16x8*)(smem + dbuf + offB[3]);
    a[4] = *(const f16x8*)(smem + dbuf + offA[4]);
    a[5] = *(const f16x8*)(smem + dbuf + offA[5]);
    a[6] = *(const f16x8*)(smem + dbuf + offA[6]);
    a[7] = *(const f16x8*)(smem + dbuf + offA[7]);

    __builtin_amdgcn_s_setprio(1);
#pragma unroll
    for (int mi = 0; mi < 8; ++mi)
#pragma unroll
      for (int ni = 0; ni < 4; ++ni)
        acc[mi][ni] = __builtin_amdgcn_mfma_f32_16x16x32_f16(a[mi], b[ni], acc[mi][ni], 0, 0, 0);
    __builtin_amdgcn_s_setprio(0);
  }

  // drain tail junk stages; then LDS is ours for the epilogue
  asm volatile("s_waitcnt vmcnt(0)" ::: "memory");
  __syncthreads();

  // ---- epilogue: wave-private transpose -> per-row approx top-4 per 64-col stripe ----
  float rv[4];
#pragma unroll
  for (int ni = 0; ni < 4; ++ni) rv[ni] = r2g[n0 + wn * 64 + ni * 16 + ln15];
  float* sw = (float*)smem + wid * 2112;   // [32][66] f32, wave-private
  const int rr = lane >> 1, hh = lane & 1;
#pragma unroll
  for (int P = 0; P < 4; ++P) {
#pragma unroll
    for (int mh = 0; mh < 2; ++mh)
#pragma unroll
      for (int ni = 0; ni < 4; ++ni)
#pragma unroll
        for (int r = 0; r < 4; ++r) {
          const int row_l = mh * 16 + g4 * 4 + r;   // C/D: col=lane&15, row=(lane>>4)*4+reg
          sw[row_l * 66 + ni * 16 + ln15] = rv[ni] - 2.0f * acc[2 * P + mh][ni][r];
        }
    asm volatile("s_waitcnt lgkmcnt(0)" ::: "memory");
    __builtin_amdgcn_sched_barrier(0);
    float s[4]  = {1e30f, 1e30f, 1e30f, 1e30f};
    int   id[4] = {0x7fffffff, 0x7fffffff, 0x7fffffff, 0x7fffffff};
    const float* rowp = sw + rr * 66 + hh * 32;
    const int cb = n0 + wn * 64 + hh * 32;
#pragma unroll
    for (int j = 0; j < 16; ++j) {
      const float2 v = *(const float2*)(rowp + j * 2);
      insert4(s, id, v.x, cb + j * 2);
      insert4(s, id, v.y, cb + j * 2 + 1);
    }
    float os[4]; int oid[4];
#pragma unroll
    for (int j = 0; j < 4; ++j) { os[j] = __shfl_xor(s[j], 1); oid[j] = __shfl_xor(id[j], 1); }
    merge_top4(s, id, os, oid);
    if (hh == 0) {
      const int q = m0 + wm * 128 + P * 32 + rr;
      const int base = (q * NL + bx * 4 + wn) * 4;
#pragma unroll
      for (int j = 0; j < 4; ++j) { pscore[base + j] = s[j]; pidx[base + j] = id[j]; }
    }
    asm volatile("s_waitcnt lgkmcnt(0)" ::: "memory");
  }
#undef STAGE_A
#undef STAGE_B
}

// ---------- merge NL partial lists per query -> approx global top-8 ----------
__global__ __launch_bounds__(64)
void select8_kernel(const float* __restrict__ pscore, const int* __restrict__ pidx,
                    int* __restrict__ cand8) {
  const int t = blockIdx.x, lane = threadIdx.x;
  float s[8]; int id[8];
#pragma unroll
  for (int j = 0; j < 8; ++j) { s[j] = 1e30f; id[j] = 0x7fffffff; }
#pragma unroll
  for (int li = 0; li < 4; ++li) {
    const int base = (t * NL + lane * 4 + li) * 4;
    const float4 sv = *(const float4*)&pscore[base];
    const int4   iv = *(const int4*)&pidx[base];
    float os[8] = {sv.x, sv.y, sv.z, sv.w, 1e30f, 1e30f, 1e30f, 1e30f};
    int  oid[8] = {iv.x, iv.y, iv.z, iv.w,
                   0x7fffffff, 0x7fffffff, 0x7fffffff, 0x7fffffff};
    merge_top8(s, id, os, oid);
  }
#pragma unroll
  for (int mask = 1; mask < 64; mask <<= 1) {
    float os[8]; int oid[8];
#pragma unroll
    for (int j = 0; j < 8; ++j) {
      os[j]  = __shfl_xor(s[j], mask);
      oid[j] = __shfl_xor(id[j], mask);
    }
    merge_top8(s, id, os, oid);
  }
  if (lane == 0) {
#pragma unroll
    for (int j = 0; j < 8; ++j) cand8[t * 8 + j] = id[j];
  }
}

// ---------- exact rescore of 8 candidates (split-f16 3-product dot) -> top-4 ----------
__global__ __launch_bounds__(256)
void rescore_kernel(const f16* __restrict__ A2, const f16* __restrict__ B2,
                    const float* __restrict__ r2, const int* __restrict__ cand8,
                    int* __restrict__ final4) {
  const int lane = threadIdx.x & 63;
  const int t = blockIdx.x * 4 + (threadIdx.x >> 6);
  const f16* xrow = A2 + (size_t)t * KP2;
  float xh[12], xl[12];
#pragma unroll
  for (int k = 0; k < 12; ++k) {
    xh[k] = (float)xrow[lane + 64 * k];
    xl[k] = (float)xrow[768 + lane + 64 * k];
  }
  int cid[8];
#pragma unroll
  for (int j = 0; j < 8; ++j) cid[j] = cand8[t * 8 + j];
  float sc[8];
#pragma unroll
  for (int j = 0; j < 8; ++j) {
    const f16* rrow = B2 + (size_t)cid[j] * KP2;
    float acc = 0.f;
#pragma unroll
    for (int k = 0; k < 12; ++k) {
      const float rh = (float)rrow[lane + 64 * k];
      const float rl = (float)rrow[768 + lane + 64 * k];
      acc = fmaf(xh[k], rh, acc);
      acc = fmaf(xh[k], rl, acc);
      acc = fmaf(xl[k], rh, acc);
    }
#pragma unroll
    for (int m = 1; m < 64; m <<= 1) acc += __shfl_xor(acc, m);
    sc[j] = r2[cid[j]] - 2.0f * acc;
  }
  if (lane == 0) {
    float s4[4] = {1e30f, 1e30f, 1e30f, 1e30f};
    int   i4[4] = {0x7fffffff, 0x7fffffff, 0x7fffffff, 0x7fffffff};
#pragma unroll
    for (int j = 0; j < 8; ++j) insert4(s4, i4, sc[j], cid[j]);
    int4 o; o.x = i4[0]; o.y = i4[1]; o.z = i4[2]; o.w = i4[3];
    *(int4*)&final4[t * 4] = o;
  }
}

// ---------- gather 4 neighbors, average, write [d][T] ----------
__global__ __launch_bounds__(256)
void gather_kernel(const float* __restrict__ R, const int* __restrict__ final4,
                   float* __restrict__ out) {
  __shared__ int ids[64][4];
  const int tx = threadIdx.x & 63, ty = threadIdx.x >> 6;
  const int t0 = blockIdx.x * 64;
  ((int*)ids)[threadIdx.x] = final4[t0 * 4 + threadIdx.x];
  __syncthreads();
  const int d = blockIdx.y * 4 + ty;
  const float* row = R + (size_t)d * N_REF;
  const float sum = row[ids[tx][0]] + row[ids[tx][1]] + row[ids[tx][2]] + row[ids[tx][3]];
  out[(size_t)d * T_Q + t0 + tx] = 0.25f * sum;
}

// ---------- fallback fp32 pipeline (round-1, known correct) ----------
#define FBM 64
#define FBN 256
#define FBK 16
#define FNL (N_REF / FBN)
__global__ __launch_bounds__(256)
void score_topk_kernel(const float* __restrict__ X, const float* __restrict__ R,
                       const float* __restrict__ r2,
                       float* __restrict__ pscore, int* __restrict__ pidx) {
  __shared__ float As[FBK][FBM];
  __shared__ float Bs[FBK][FBN];
  __shared__ float r2s[FBN];
  const int tid = threadIdx.x;
  const int tx = tid & 15, ty = tid >> 4;
  const int m0 = blockIdx.y * FBM;
  const int n0 = blockIdx.x * FBN;
  r2s[tid] = r2[n0 + tid];
  float acc[4][16];
#pragma unroll
  for (int i = 0; i < 4; ++i)
#pragma unroll
    for (int j = 0; j < 16; ++j) acc[i][j] = 0.f;
  for (int k0 = 0; k0 < DIM; k0 += FBK) {
    {
      const int k = tid >> 4, m4 = tid & 15;
      const float4 av = *(const float4*)&X[(size_t)(k0 + k) * T_Q + m0 + m4 * 4];
      *(float4*)&As[k][m4 * 4] = av;
    }
#pragma unroll
    for (int i = 0; i < 4; ++i) {
      const int idx4 = tid + i * 256;
      const int k = idx4 >> 6, n4 = idx4 & 63;
      const float4 bv = *(const float4*)&R[(size_t)(k0 + k) * N_REF + n0 + n4 * 4];
      *(float4*)&Bs[k][n4 * 4] = bv;
    }
    __syncthreads();
#pragma unroll
    for (int k = 0; k < FBK; ++k) {
      float av[4], bv[16];
      *(float4*)av = *(const float4*)&As[k][ty * 4];
#pragma unroll
      for (int c = 0; c < 4; ++c)
        *(float4*)&bv[c * 4] = *(const float4*)&Bs[k][tx * 4 + c * 64];
#pragma unroll
      for (int mi = 0; mi < 4; ++mi)
#pragma unroll
        for (int ni = 0; ni < 16; ++ni) acc[mi][ni] += av[mi] * bv[ni];
    }
    __syncthreads();
  }
#pragma unroll
  for (int mi = 0; mi < 4; ++mi) {
    float s[4]  = {1e30f, 1e30f, 1e30f, 1e30f};
    int   id[4] = {0x7fffffff, 0x7fffffff, 0x7fffffff, 0x7fffffff};
#pragma unroll
    for (int c = 0; c < 4; ++c)
#pragma unroll
      for (int j = 0; j < 4; ++j) {
        const int nl = tx * 4 + c * 64 + j;
        const float sc = r2s[nl] - 2.0f * acc[mi][c * 4 + j];
        insert4(s, id, sc, n0 + nl);
      }
#pragma unroll
    for (int mask = 1; mask < 16; mask <<= 1) {
      float os[4]; int oid[4];
#pragma unroll
      for (int j = 0; j < 4; ++j) {
        os[j]  = __shfl_xor(s[j], mask);
        oid[j] = __shfl_xor(id[j], mask);
      }
      merge_top4(s, id, os, oid);
    }
    if (tx == 0) {
      const int t = m0 + ty * 4 + mi;
      const int base = (t * FNL + (int)blockIdx.x) * 4;
#pragma unroll
      for (int j = 0; j < 4; ++j) { pscore[base + j] = s[j]; pidx[base + j] = id[j]; }
    }
  }
}

template <int NLISTS>
__global__ __launch_bounds__(64)
void select_kernel(const float* __restrict__ pscore, const int* __restrict__ pidx,
                   int* __restrict__ final4) {
  const int t = blockIdx.x, lane = threadIdx.x;
  constexpr int LPL = NLISTS / 64;
  float s[4]  = {1e30f, 1e30f, 1e30f, 1e30f};
  int   id[4] = {0x7fffffff, 0x7fffffff, 0x7fffffff, 0x7fffffff};
#pragma unroll
  for (int li = 0; li < LPL; ++li) {
    const int base = (t * NLISTS + lane * LPL + li) * 4;
    const float4 sv = *(const float4*)&pscore[base];
    const int4   iv = *(const int4*)&pidx[base];
    float os[4] = {sv.x, sv.y, sv.z, sv.w};
    int  oid[4] = {iv.x, iv.y, iv.z, iv.w};
    merge_top4(s, id, os, oid);
  }
#pragma unroll
  for (int mask = 1; mask < 64; mask <<= 1) {
    float os[4]; int oid[4];
#pragma unroll
    for (int j = 0; j < 4; ++j) {
      os[j]  = __shfl_xor(s[j], mask);
      oid[j] = __shfl_xor(id[j], mask);
    }
    merge_top4(s, id, os, oid);
  }
  if (lane == 0) {
    int4 o; o.x = id[0]; o.y = id[1]; o.z = id[2]; o.w = id[3];
    *(int4*)&final4[t * 4] = o;
  }
}

extern "C" void kernel_launch(void* const* d_in, const int* in_sizes, int n_in,
                              void* d_out, int out_size, void* d_ws, size_t ws_size,
                              hipStream_t stream) {
  const float* X = (const float*)d_in[0];   // [768][2048]
  const float* R = (const float*)d_in[1];   // [768][16384]
  float* out = (float*)d_out;               // [768][2048]

  const size_t szA2 = (size_t)T_Q * KP2 * sizeof(f16);       // 6,291,456
  const size_t szB2 = (size_t)N_REF * KP2 * sizeof(f16);     // 50,331,648
  const size_t szr2 = (size_t)N_REF * sizeof(float);         // 65,536
  const size_t szPS = (size_t)T_Q * NL * 4 * sizeof(float);  // 8,388,608
  const size_t szC8 = (size_t)T_Q * 8 * sizeof(int);         // 65,536
  const size_t need = szA2 + szB2 + szr2 + 2 * szPS + szC8 +
                      (size_t)T_Q * 4 * sizeof(int);

  if (ws_size >= need) {
    char* w = (char*)d_ws;
    f16* A2 = (f16*)w;            w += szA2;
    f16* B2 = (f16*)w;            w += szB2;
    float* r2     = (float*)w;    w += szr2;
    float* pscore = (float*)w;    w += szPS;
    int*   pidx   = (int*)w;      w += szPS;
    int*   cand8  = (int*)w;      w += szC8;
    int*   final4 = (int*)w;

    hipLaunchKernelGGL(r2_kernel, dim3(N_REF / 64), dim3(256), 0, stream, R, r2);
    hipLaunchKernelGGL(tsplit_kernel, dim3(T_Q / 64, DIM / 64), dim3(256), 0, stream,
                       X, A2, T_Q);
    hipLaunchKernelGGL(tsplit_kernel, dim3(N_REF / 64, DIM / 64), dim3(256), 0, stream,
                       R, B2, N_REF);
    hipLaunchKernelGGL(mfma_hi_topk_kernel, dim3((N_REF / BN) * (T_Q / BM)), dim3(512), 0,
                       stream, A2, B2, r2, pscore, pidx);
    hipLaunchKernelGGL(select8_kernel, dim3(T_Q), dim3(64), 0, stream,
                       pscore, pidx, cand8);
    hipLaunchKernelGGL(rescore_kernel, dim3(T_Q / 4), dim3(256), 0, stream,
                       A2, B2, r2, cand8, final4);
    hipLaunchKernelGGL(gather_kernel, dim3(T_Q / 64, DIM / 4), dim3(256), 0, stream,
                       R, final4, out);
  } else {
    // fallback: fp32 pipeline (~4.2 MB ws)
    char* w = (char*)d_ws;
    float* r2     = (float*)w;  w += szr2;
    float* pscore = (float*)w;  w += (size_t)T_Q * FNL * 4 * sizeof(float);
    int*   pidx   = (int*)w;    w += (size_t)T_Q * FNL * 4 * sizeof(int);
    int*   final4 = (int*)w;

    hipLaunchKernelGGL(r2_kernel, dim3(N_REF / 64), dim3(256), 0, stream, R, r2);
    hipLaunchKernelGGL(score_topk_kernel, dim3(N_REF / FBN, T_Q / FBM), dim3(256), 0, stream,
                       X, R, r2, pscore, pidx);
    hipLaunchKernelGGL((select_kernel<FNL>), dim3(T_Q), dim3(64), 0, stream,
                       pscore, pidx, final4);
    hipLaunchKernelGGL(gather_kernel, dim3(T_Q / 64, DIM / 4), dim3(256), 0, stream,
                       R, final4, out);
  }
}

// Round 11
// 178.389 us; speedup vs baseline: 7.5824x; 1.0564x over previous
//
#include <hip/hip_runtime.h>
#include <stdint.h>

#define T_Q   2048
#define N_REF 16384
#define DIM   768
#define KP2   1536        // packed K cols: [hi | lo]
#define NT    24          // K = 768 = 24 tiles of 32 (hi limb only)
#define NL    256         // partial top-4 lists per query (64-col stripes)

using f16   = _Float16;
using f16x4 = __attribute__((ext_vector_type(4))) _Float16;
using f16x8 = __attribute__((ext_vector_type(8))) _Float16;
using f32x4 = __attribute__((ext_vector_type(4))) float;

// ---------- lexicographic top-k helpers (static indices only) ----------
__device__ __forceinline__ bool lex_less(float sa, int ia, float sb, int ib) {
  return (sa < sb) || (sa == sb && ia < ib);
}
#define CE_PAIR(s0, i0, s1, i1)                                        \
  { if (lex_less(s1, i1, s0, i0)) { float _ts = s0; s0 = s1; s1 = _ts; \
                                    int _ti = i0; i0 = i1; i1 = _ti; } }
#define PICKMIN(as, ai, bs, bi, rs, ri)                   \
  { if (lex_less(bs, bi, as, ai)) { rs = bs; ri = bi; }   \
    else                          { rs = as; ri = ai; } }

__device__ __forceinline__ void insert4(float s[4], int id[4], float sc, int n) {
  if (lex_less(sc, n, s[3], id[3])) {
    s[3] = sc; id[3] = n;
    CE_PAIR(s[2], id[2], s[3], id[3]);
    CE_PAIR(s[1], id[1], s[2], id[2]);
    CE_PAIR(s[0], id[0], s[1], id[1]);
  }
}
__device__ __forceinline__ void merge_top4(float s[4], int id[4],
                                           const float os[4], const int oid[4]) {
  float l0, l1, l2, l3; int j0, j1, j2, j3;
  PICKMIN(s[0], id[0], os[3], oid[3], l0, j0);
  PICKMIN(s[1], id[1], os[2], oid[2], l1, j1);
  PICKMIN(s[2], id[2], os[1], oid[1], l2, j2);
  PICKMIN(s[3], id[3], os[0], oid[0], l3, j3);
  CE_PAIR(l0, j0, l2, j2);
  CE_PAIR(l1, j1, l3, j3);
  CE_PAIR(l0, j0, l1, j1);
  CE_PAIR(l2, j2, l3, j3);
  s[0] = l0; s[1] = l1; s[2] = l2; s[3] = l3;
  id[0] = j0; id[1] = j1; id[2] = j2; id[3] = j3;
}

// merge two sorted(asc) 8-lists, keep smallest 8 (Batcher bitonic lower half)
__device__ __forceinline__ void merge_top8(float s[8], int id[8],
                                           const float os[8], const int oid[8]) {
  float l0,l1,l2,l3,l4,l5,l6,l7; int j0,j1,j2,j3,j4,j5,j6,j7;
  PICKMIN(s[0], id[0], os[7], oid[7], l0, j0);
  PICKMIN(s[1], id[1], os[6], oid[6], l1, j1);
  PICKMIN(s[2], id[2], os[5], oid[5], l2, j2);
  PICKMIN(s[3], id[3], os[4], oid[4], l3, j3);
  PICKMIN(s[4], id[4], os[3], oid[3], l4, j4);
  PICKMIN(s[5], id[5], os[2], oid[2], l5, j5);
  PICKMIN(s[6], id[6], os[1], oid[1], l6, j6);
  PICKMIN(s[7], id[7], os[0], oid[0], l7, j7);
  CE_PAIR(l0, j0, l4, j4); CE_PAIR(l1, j1, l5, j5);
  CE_PAIR(l2, j2, l6, j6); CE_PAIR(l3, j3, l7, j7);
  CE_PAIR(l0, j0, l2, j2); CE_PAIR(l1, j1, l3, j3);
  CE_PAIR(l4, j4, l6, j6); CE_PAIR(l5, j5, l7, j7);
  CE_PAIR(l0, j0, l1, j1); CE_PAIR(l2, j2, l3, j3);
  CE_PAIR(l4, j4, l5, j5); CE_PAIR(l6, j6, l7, j7);
  s[0]=l0; s[1]=l1; s[2]=l2; s[3]=l3; s[4]=l4; s[5]=l5; s[6]=l6; s[7]=l7;
  id[0]=j0; id[1]=j1; id[2]=j2; id[3]=j3; id[4]=j4; id[5]=j5; id[6]=j6; id[7]=j7;
}

__device__ __forceinline__ void gl_lds16(const void* g, void* l) {
  __builtin_amdgcn_global_load_lds((const __attribute__((address_space(1))) uint32_t*)g,
                                   (__attribute__((address_space(3))) uint32_t*)l, 16, 0, 0);
}

// ---------- r2[n] = ||ref_n||^2 (fp32 exact) ----------
__global__ __launch_bounds__(256)
void r2_kernel(const float* __restrict__ R, float* __restrict__ r2) {
  __shared__ float red[256];
  const int lane = threadIdx.x & 63;
  const int dg   = threadIdx.x >> 6;
  const int n    = blockIdx.x * 64 + lane;
  float acc = 0.f;
  const int d0 = dg * (DIM / 4), d1 = d0 + (DIM / 4);
  for (int d = d0; d < d1; ++d) {
    float v = R[(size_t)d * N_REF + n];
    acc += v * v;
  }
  red[threadIdx.x] = acc;
  __syncthreads();
  if (threadIdx.x < 64)
    r2[n] = red[lane] + red[lane + 64] + red[lane + 128] + red[lane + 192];
}

// ---------- transpose + f16 hi/lo split: in[D][W] -> out[W][1536] = [hi | lo] ----------
__global__ __launch_bounds__(256)
void tsplit_kernel(const float* __restrict__ in, f16* __restrict__ out, int W) {
  __shared__ f16 lh[64][66], ll[64][66];
  const int c0 = blockIdx.x * 64, d0 = blockIdx.y * 64;
  const int q = threadIdx.x & 15, p = threadIdx.x >> 4;
#pragma unroll
  for (int i = 0; i < 4; ++i) {
    const int dl = p + i * 16;
    const float4 v = *(const float4*)&in[(size_t)(d0 + dl) * W + c0 + q * 4];
    const f16 h0 = (f16)v.x, h1 = (f16)v.y, h2 = (f16)v.z, h3 = (f16)v.w;
    lh[q * 4 + 0][dl] = h0; ll[q * 4 + 0][dl] = (f16)(v.x - (float)h0);
    lh[q * 4 + 1][dl] = h1; ll[q * 4 + 1][dl] = (f16)(v.y - (float)h1);
    lh[q * 4 + 2][dl] = h2; ll[q * 4 + 2][dl] = (f16)(v.z - (float)h2);
    lh[q * 4 + 3][dl] = h3; ll[q * 4 + 3][dl] = (f16)(v.w - (float)h3);
  }
  __syncthreads();
  const int rl = threadIdx.x >> 2, seg = threadIdx.x & 3;
  f16* rowo = out + (size_t)(c0 + rl) * KP2 + d0;
#pragma unroll
  for (int j = 0; j < 4; ++j) {
    const int dd = seg * 16 + j * 4;
    f16x4 vh = *(const f16x4*)&lh[rl][dd];
    f16x4 vl = *(const f16x4*)&ll[rl][dd];
    *(f16x4*)&rowo[dd] = vh;
    *(f16x4*)&rowo[768 + dd] = vl;
  }
}

// ---------- m97-geometry 128x128 f16-hi MFMA GEMM + fused approx top-4 ----------
// 4 waves (2x2), BK=32, 2-buf depth-1, 2 barriers + vmcnt(4)/tile.
// LDS 33.8 KB, acc 64 AGPR -> ~3 blocks/CU: cross-block overlap hides stalls
// (m114 mechanism; the 256-tile designs at 1 block/CU had none).
__global__ __launch_bounds__(256, 2)
void mfma128_topk_kernel(const f16* __restrict__ A2, const f16* __restrict__ B2,
                         const float* __restrict__ r2g,
                         float* __restrict__ pscore, int* __restrict__ pidx) {
  // GEMM: buf q at q*16384: A @0 (8 KB), B @8192 (8 KB).
  // Region: 128 rows x 32 K-cols f16 (64 B rows); 16B slot swizzle: slot ^= (row>>1)&3.
  // Epilogue reuses [0, 33792): 4 waves x [32][66] f32.
  __shared__ __align__(16) char smem[33792];
  const int tid  = threadIdx.x;
  const int lane = tid & 63, wid = tid >> 6;
  const int wm = wid >> 1, wn = wid & 1;
  const int ln15 = lane & 15, g4 = lane >> 4;

  // supertile XCD mapping: XCD (flat&7) owns bx in [16x, 16x+16), all by
  const int flat = (int)blockIdx.x;
  const int jj = flat >> 3;
  const int bx = (flat & 7) * 16 + (jj & 15);  // 0..127
  const int by = jj >> 4;                      // 0..15
  const int m0 = by * 128, n0 = bx * 128;

  // staging: per matrix per tile 8 KB = 512 slots; thread t handles slots t, t+256.
  // LDS slot s: row = s>>2 (0..127), lslot = s&3 ; global slot = lslot ^ ((s>>3)&3)
  const int s0 = tid, s1 = tid + 256;
  const int r0 = s0 >> 2, r1 = s1 >> 2;
  const int c0b = (((s0 & 3) ^ ((s0 >> 3) & 3)) << 4);
  const int c1b = (((s1 & 3) ^ ((s1 >> 3) & 3)) << 4);
  const char* gA0 = (const char*)(A2 + (size_t)(m0 + r0) * KP2) + c0b;
  const char* gA1 = (const char*)(A2 + (size_t)(m0 + r1) * KP2) + c1b;
  const char* gB0 = (const char*)(B2 + (size_t)(n0 + r0) * KP2) + c0b;
  const char* gB1 = (const char*)(B2 + (size_t)(n0 + r1) * KP2) + c1b;
  const int l0 = s0 * 16, l1 = s1 * 16;

#define STAGE_A(bufo, kbyte)                                     \
  { gl_lds16(gA0 + (kbyte), smem + (bufo) + l0);                 \
    gl_lds16(gA1 + (kbyte), smem + (bufo) + l1); }
#define STAGE_B(bufo, kbyte)                                     \
  { gl_lds16(gB0 + (kbyte), smem + (bufo) + 8192 + l0);          \
    gl_lds16(gB1 + (kbyte), smem + (bufo) + 8192 + l1); }

  // fragment LDS offsets (K-invariant): lane reads global slot g4 of its row
  const int cswz = ((g4 ^ ((ln15 >> 1) & 3)) << 4);
  int offA[4], offB[4];
#pragma unroll
  for (int mi = 0; mi < 4; ++mi) offA[mi] = (wm * 64 + mi * 16 + ln15) * 64 + cswz;
#pragma unroll
  for (int ni = 0; ni < 4; ++ni) offB[ni] = 8192 + (wn * 64 + ni * 16 + ln15) * 64 + cswz;

  f32x4 acc[4][4] = {};

  // prologue: stage tile 0 -> buf0 (4 loads outstanding)
  STAGE_A(0, 0);
  STAGE_B(0, 0);

  for (int kt = 0; kt < NT; ++kt) {
    const int dbuf = (kt & 1) << 14;
    const int sdb  = ((kt + 1) & 1) << 14;
    const int ktn = (kt + 1 < NT) ? kt + 1 : NT - 1;   // tail: restage last (never read)

    // stage next tile into the other buffer (its old contents were consumed
    // before the trailing barrier of iter kt-1 that every wave already crossed)
    STAGE_A(sdb, ktn * 64);
    STAGE_B(sdb, ktn * 64);
    // retire THIS tile's 4 loads (8 -> 4 outstanding), then collective barrier
    asm volatile("s_waitcnt vmcnt(4)" ::: "memory");
    asm volatile("s_barrier" ::: "memory");

    f16x8 a[4], b[4];
    a[0] = *(const f16x8*)(smem + dbuf + offA[0]);
    b[0] = *(const f16x8*)(smem + dbuf + offB[0]);
    a[1] = *(const f16x8*)(smem + dbuf + offA[1]);
    b[1] = *(const f16x8*)(smem + dbuf + offB[1]);
    a[2] = *(const f16x8*)(smem + dbuf + offA[2]);
    b[2] = *(const f16x8*)(smem + dbuf + offB[2]);
    a[3] = *(const f16x8*)(smem + dbuf + offA[3]);
    b[3] = *(const f16x8*)(smem + dbuf + offB[3]);

    __builtin_amdgcn_s_setprio(1);
#pragma unroll
    for (int mi = 0; mi < 4; ++mi)
#pragma unroll
      for (int ni = 0; ni < 4; ++ni)
        acc[mi][ni] = __builtin_amdgcn_mfma_f32_16x16x32_f16(a[mi], b[ni], acc[mi][ni], 0, 0, 0);
    __builtin_amdgcn_s_setprio(0);
    // trailing barrier: all waves consumed dbuf before next iter stages it
    asm volatile("s_barrier" ::: "memory");
  }

  // drain tail junk stages; then LDS is ours for the epilogue
  asm volatile("s_waitcnt vmcnt(0)" ::: "memory");
  __syncthreads();

  // ---- epilogue: wave-private transpose -> per-row approx top-4 per 64-col stripe ----
  float rv[4];
#pragma unroll
  for (int ni = 0; ni < 4; ++ni) rv[ni] = r2g[n0 + wn * 64 + ni * 16 + ln15];
  float* sw = (float*)smem + wid * 2112;   // [32][66] f32, wave-private
  const int rr = lane >> 1, hh = lane & 1;
#pragma unroll
  for (int P = 0; P < 2; ++P) {
#pragma unroll
    for (int mh = 0; mh < 2; ++mh)
#pragma unroll
      for (int ni = 0; ni < 4; ++ni)
#pragma unroll
        for (int r = 0; r < 4; ++r) {
          const int row_l = mh * 16 + g4 * 4 + r;   // C/D: col=lane&15, row=(lane>>4)*4+reg
          sw[row_l * 66 + ni * 16 + ln15] = rv[ni] - 2.0f * acc[2 * P + mh][ni][r];
        }
    asm volatile("s_waitcnt lgkmcnt(0)" ::: "memory");
    __builtin_amdgcn_sched_barrier(0);
    float s[4]  = {1e30f, 1e30f, 1e30f, 1e30f};
    int   id[4] = {0x7fffffff, 0x7fffffff, 0x7fffffff, 0x7fffffff};
    const float* rowp = sw + rr * 66 + hh * 32;
    const int cb = n0 + wn * 64 + hh * 32;
#pragma unroll
    for (int j = 0; j < 16; ++j) {
      const float2 v = *(const float2*)(rowp + j * 2);
      insert4(s, id, v.x, cb + j * 2);
      insert4(s, id, v.y, cb + j * 2 + 1);
    }
    float os[4]; int oid[4];
#pragma unroll
    for (int j = 0; j < 4; ++j) { os[j] = __shfl_xor(s[j], 1); oid[j] = __shfl_xor(id[j], 1); }
    merge_top4(s, id, os, oid);
    if (hh == 0) {
      const int q = m0 + wm * 64 + P * 32 + rr;
      const int base = (q * NL + bx * 2 + wn) * 4;
#pragma unroll
      for (int j = 0; j < 4; ++j) { pscore[base + j] = s[j]; pidx[base + j] = id[j]; }
    }
    asm volatile("s_waitcnt lgkmcnt(0)" ::: "memory");
  }
#undef STAGE_A
#undef STAGE_B
}

// ---------- merge NL partial lists per query -> approx global top-8 ----------
__global__ __launch_bounds__(64)
void select8_kernel(const float* __restrict__ pscore, const int* __restrict__ pidx,
                    int* __restrict__ cand8) {
  const int t = blockIdx.x, lane = threadIdx.x;
  float s[8]; int id[8];
#pragma unroll
  for (int j = 0; j < 8; ++j) { s[j] = 1e30f; id[j] = 0x7fffffff; }
#pragma unroll
  for (int li = 0; li < 4; ++li) {
    const int base = (t * NL + lane * 4 + li) * 4;
    const float4 sv = *(const float4*)&pscore[base];
    const int4   iv = *(const int4*)&pidx[base];
    float os[8] = {sv.x, sv.y, sv.z, sv.w, 1e30f, 1e30f, 1e30f, 1e30f};
    int  oid[8] = {iv.x, iv.y, iv.z, iv.w,
                   0x7fffffff, 0x7fffffff, 0x7fffffff, 0x7fffffff};
    merge_top8(s, id, os, oid);
  }
#pragma unroll
  for (int mask = 1; mask < 64; mask <<= 1) {
    float os[8]; int oid[8];
#pragma unroll
    for (int j = 0; j < 8; ++j) {
      os[j]  = __shfl_xor(s[j], mask);
      oid[j] = __shfl_xor(id[j], mask);
    }
    merge_top8(s, id, os, oid);
  }
  if (lane == 0) {
#pragma unroll
    for (int j = 0; j < 8; ++j) cand8[t * 8 + j] = id[j];
  }
}

// ---------- exact rescore of 8 candidates (split-f16 3-product dot) -> top-4 ----------
__global__ __launch_bounds__(256)
void rescore_kernel(const f16* __restrict__ A2, const f16* __restrict__ B2,
                    const float* __restrict__ r2, const int* __restrict__ cand8,
                    int* __restrict__ final4) {
  const int lane = threadIdx.x & 63;
  const int t = blockIdx.x * 4 + (threadIdx.x >> 6);
  const f16* xrow = A2 + (size_t)t * KP2;
  float xh[12], xl[12];
#pragma unroll
  for (int k = 0; k < 12; ++k) {
    xh[k] = (float)xrow[lane + 64 * k];
    xl[k] = (float)xrow[768 + lane + 64 * k];
  }
  int cid[8];
#pragma unroll
  for (int j = 0; j < 8; ++j) cid[j] = cand8[t * 8 + j];
  float sc[8];
#pragma unroll
  for (int j = 0; j < 8; ++j) {
    const f16* rrow = B2 + (size_t)cid[j] * KP2;
    float acc = 0.f;
#pragma unroll
    for (int k = 0; k < 12; ++k) {
      const float rh = (float)rrow[lane + 64 * k];
      const float rl = (float)rrow[768 + lane + 64 * k];
      acc = fmaf(xh[k], rh, acc);
      acc = fmaf(xh[k], rl, acc);
      acc = fmaf(xl[k], rh, acc);
    }
#pragma unroll
    for (int m = 1; m < 64; m <<= 1) acc += __shfl_xor(acc, m);
    sc[j] = r2[cid[j]] - 2.0f * acc;
  }
  if (lane == 0) {
    float s4[4] = {1e30f, 1e30f, 1e30f, 1e30f};
    int   i4[4] = {0x7fffffff, 0x7fffffff, 0x7fffffff, 0x7fffffff};
#pragma unroll
    for (int j = 0; j < 8; ++j) insert4(s4, i4, sc[j], cid[j]);
    int4 o; o.x = i4[0]; o.y = i4[1]; o.z = i4[2]; o.w = i4[3];
    *(int4*)&final4[t * 4] = o;
  }
}

// ---------- gather 4 neighbors, average, write [d][T] ----------
__global__ __launch_bounds__(256)
void gather_kernel(const float* __restrict__ R, const int* __restrict__ final4,
                   float* __restrict__ out) {
  __shared__ int ids[64][4];
  const int tx = threadIdx.x & 63, ty = threadIdx.x >> 6;
  const int t0 = blockIdx.x * 64;
  ((int*)ids)[threadIdx.x] = final4[t0 * 4 + threadIdx.x];
  __syncthreads();
  const int d = blockIdx.y * 4 + ty;
  const float* row = R + (size_t)d * N_REF;
  const float sum = row[ids[tx][0]] + row[ids[tx][1]] + row[ids[tx][2]] + row[ids[tx][3]];
  out[(size_t)d * T_Q + t0 + tx] = 0.25f * sum;
}

// ---------- fallback fp32 pipeline (round-1, known correct) ----------
#define FBM 64
#define FBN 256
#define FBK 16
#define FNL (N_REF / FBN)
__global__ __launch_bounds__(256)
void score_topk_kernel(const float* __restrict__ X, const float* __restrict__ R,
                       const float* __restrict__ r2,
                       float* __restrict__ pscore, int* __restrict__ pidx) {
  __shared__ float As[FBK][FBM];
  __shared__ float Bs[FBK][FBN];
  __shared__ float r2s[FBN];
  const int tid = threadIdx.x;
  const int tx = tid & 15, ty = tid >> 4;
  const int m0 = blockIdx.y * FBM;
  const int n0 = blockIdx.x * FBN;
  r2s[tid] = r2[n0 + tid];
  float acc[4][16];
#pragma unroll
  for (int i = 0; i < 4; ++i)
#pragma unroll
    for (int j = 0; j < 16; ++j) acc[i][j] = 0.f;
  for (int k0 = 0; k0 < DIM; k0 += FBK) {
    {
      const int k = tid >> 4, m4 = tid & 15;
      const float4 av = *(const float4*)&X[(size_t)(k0 + k) * T_Q + m0 + m4 * 4];
      *(float4*)&As[k][m4 * 4] = av;
    }
#pragma unroll
    for (int i = 0; i < 4; ++i) {
      const int idx4 = tid + i * 256;
      const int k = idx4 >> 6, n4 = idx4 & 63;
      const float4 bv = *(const float4*)&R[(size_t)(k0 + k) * N_REF + n0 + n4 * 4];
      *(float4*)&Bs[k][n4 * 4] = bv;
    }
    __syncthreads();
#pragma unroll
    for (int k = 0; k < FBK; ++k) {
      float av[4], bv[16];
      *(float4*)av = *(const float4*)&As[k][ty * 4];
#pragma unroll
      for (int c = 0; c < 4; ++c)
        *(float4*)&bv[c * 4] = *(const float4*)&Bs[k][tx * 4 + c * 64];
#pragma unroll
      for (int mi = 0; mi < 4; ++mi)
#pragma unroll
        for (int ni = 0; ni < 16; ++ni) acc[mi][ni] += av[mi] * bv[ni];
    }
    __syncthreads();
  }
#pragma unroll
  for (int mi = 0; mi < 4; ++mi) {
    float s[4]  = {1e30f, 1e30f, 1e30f, 1e30f};
    int   id[4] = {0x7fffffff, 0x7fffffff, 0x7fffffff, 0x7fffffff};
#pragma unroll
    for (int c = 0; c < 4; ++c)
#pragma unroll
      for (int j = 0; j < 4; ++j) {
        const int nl = tx * 4 + c * 64 + j;
        const float sc = r2s[nl] - 2.0f * acc[mi][c * 4 + j];
        insert4(s, id, sc, n0 + nl);
      }
#pragma unroll
    for (int mask = 1; mask < 16; mask <<= 1) {
      float os[4]; int oid[4];
#pragma unroll
      for (int j = 0; j < 4; ++j) {
        os[j]  = __shfl_xor(s[j], mask);
        oid[j] = __shfl_xor(id[j], mask);
      }
      merge_top4(s, id, os, oid);
    }
    if (tx == 0) {
      const int t = m0 + ty * 4 + mi;
      const int base = (t * FNL + (int)blockIdx.x) * 4;
#pragma unroll
      for (int j = 0; j < 4; ++j) { pscore[base + j] = s[j]; pidx[base + j] = id[j]; }
    }
  }
}

template <int NLISTS>
__global__ __launch_bounds__(64)
void select_kernel(const float* __restrict__ pscore, const int* __restrict__ pidx,
                   int* __restrict__ final4) {
  const int t = blockIdx.x, lane = threadIdx.x;
  constexpr int LPL = NLISTS / 64;
  float s[4]  = {1e30f, 1e30f, 1e30f, 1e30f};
  int   id[4] = {0x7fffffff, 0x7fffffff, 0x7fffffff, 0x7fffffff};
#pragma unroll
  for (int li = 0; li < LPL; ++li) {
    const int base = (t * NLISTS + lane * LPL + li) * 4;
    const float4 sv = *(const float4*)&pscore[base];
    const int4   iv = *(const int4*)&pidx[base];
    float os[4] = {sv.x, sv.y, sv.z, sv.w};
    int  oid[4] = {iv.x, iv.y, iv.z, iv.w};
    merge_top4(s, id, os, oid);
  }
#pragma unroll
  for (int mask = 1; mask < 64; mask <<= 1) {
    float os[4]; int oid[4];
#pragma unroll
    for (int j = 0; j < 4; ++j) {
      os[j]  = __shfl_xor(s[j], mask);
      oid[j] = __shfl_xor(id[j], mask);
    }
    merge_top4(s, id, os, oid);
  }
  if (lane == 0) {
    int4 o; o.x = id[0]; o.y = id[1]; o.z = id[2]; o.w = id[3];
    *(int4*)&final4[t * 4] = o;
  }
}

extern "C" void kernel_launch(void* const* d_in, const int* in_sizes, int n_in,
                              void* d_out, int out_size, void* d_ws, size_t ws_size,
                              hipStream_t stream) {
  const float* X = (const float*)d_in[0];   // [768][2048]
  const float* R = (const float*)d_in[1];   // [768][16384]
  float* out = (float*)d_out;               // [768][2048]

  const size_t szA2 = (size_t)T_Q * KP2 * sizeof(f16);       // 6,291,456
  const size_t szB2 = (size_t)N_REF * KP2 * sizeof(f16);     // 50,331,648
  const size_t szr2 = (size_t)N_REF * sizeof(float);         // 65,536
  const size_t szPS = (size_t)T_Q * NL * 4 * sizeof(float);  // 8,388,608
  const size_t szC8 = (size_t)T_Q * 8 * sizeof(int);         // 65,536
  const size_t need = szA2 + szB2 + szr2 + 2 * szPS + szC8 +
                      (size_t)T_Q * 4 * sizeof(int);

  if (ws_size >= need) {
    char* w = (char*)d_ws;
    f16* A2 = (f16*)w;            w += szA2;
    f16* B2 = (f16*)w;            w += szB2;
    float* r2     = (float*)w;    w += szr2;
    float* pscore = (float*)w;    w += szPS;
    int*   pidx   = (int*)w;      w += szPS;
    int*   cand8  = (int*)w;      w += szC8;
    int*   final4 = (int*)w;

    hipLaunchKernelGGL(r2_kernel, dim3(N_REF / 64), dim3(256), 0, stream, R, r2);
    hipLaunchKernelGGL(tsplit_kernel, dim3(T_Q / 64, DIM / 64), dim3(256), 0, stream,
                       X, A2, T_Q);
    hipLaunchKernelGGL(tsplit_kernel, dim3(N_REF / 64, DIM / 64), dim3(256), 0, stream,
                       R, B2, N_REF);
    hipLaunchKernelGGL(mfma128_topk_kernel, dim3((N_REF / 128) * (T_Q / 128)), dim3(256), 0,
                       stream, A2, B2, r2, pscore, pidx);
    hipLaunchKernelGGL(select8_kernel, dim3(T_Q), dim3(64), 0, stream,
                       pscore, pidx, cand8);
    hipLaunchKernelGGL(rescore_kernel, dim3(T_Q / 4), dim3(256), 0, stream,
                       A2, B2, r2, cand8, final4);
    hipLaunchKernelGGL(gather_kernel, dim3(T_Q / 64, DIM / 4), dim3(256), 0, stream,
                       R, final4, out);
  } else {
    // fallback: fp32 pipeline (~4.2 MB ws)
    char* w = (char*)d_ws;
    float* r2     = (float*)w;  w += szr2;
    float* pscore = (float*)w;  w += (size_t)T_Q * FNL * 4 * sizeof(float);
    int*   pidx   = (int*)w;    w += (size_t)T_Q * FNL * 4 * sizeof(int);
    int*   final4 = (int*)w;

    hipLaunchKernelGGL(r2_kernel, dim3(N_REF / 64), dim3(256), 0, stream, R, r2);
    hipLaunchKernelGGL(score_topk_kernel, dim3(N_REF / FBN, T_Q / FBM), dim3(256), 0, stream,
                       X, R, r2, pscore, pidx);
    hipLaunchKernelGGL((select_kernel<FNL>), dim3(T_Q), dim3(64), 0, stream,
                       pscore, pidx, final4);
    hipLaunchKernelGGL(gather_kernel, dim3(T_Q / 64, DIM / 4), dim3(256), 0, stream,
                       R, final4, out);
  }
}